// Round 5
// baseline (801.555 us; speedup 1.0000x reference)
//
#include <hip/hip_runtime.h>

typedef unsigned short u16;
typedef unsigned int u32;
typedef short short8 __attribute__((ext_vector_type(8)));
typedef float f32x4 __attribute__((ext_vector_type(4)));

#define NB 4
#define NS 2048
#define NSTATE 1024
#define NH 16
#define ND 64
#define NM (NB*NS)   // 8192 rows

#if __has_builtin(__builtin_amdgcn_exp2f)
#define EXP2(x) __builtin_amdgcn_exp2f(x)
#else
#define EXP2(x) __expf((x) * 0.6931471805599453f)
#endif

__device__ __forceinline__ u16 f2bf(float f){
  union { float fv; unsigned uv; } x; x.fv = f;
  unsigned r = x.uv + 0x7fffu + ((x.uv >> 16) & 1u);
  return (u16)(r >> 16);
}

__device__ __forceinline__ u32 cvtpk(float lo, float hi){
  u32 r;
  asm("v_cvt_pk_bf16_f32 %0, %1, %2" : "=v"(r) : "v"(lo), "v"(hi));
  return r;
}

__device__ __forceinline__ f32x4 mfma16x16(short8 a, short8 b, f32x4 c){
  return __builtin_amdgcn_mfma_f32_16x16x32_bf16(a, b, c, 0, 0, 0);
}

__device__ __forceinline__ void gld_lds16(const u16* g, u16* l){
  __builtin_amdgcn_global_load_lds((const __attribute__((address_space(1))) void*)g,
                                   (__attribute__((address_space(3))) void*)l, 16, 0, 0);
}

// ---------------- fp32 -> bf16 conversion for 3 activations + 4 weights ----
__global__ __launch_bounds__(256)
void cvt_all(const float* __restrict__ q, const float* __restrict__ k, const float* __restrict__ v,
             const float* __restrict__ wq, const float* __restrict__ wk,
             const float* __restrict__ wv, const float* __restrict__ wo,
             u16* oq, u16* ok, u16* ov, u16* owq, u16* owk, u16* owv, u16* owo){
  const int XN4 = (NB*NS*NSTATE)/4;   // 2097152
  const int WN4 = (NSTATE*NSTATE)/4;  // 262144
  int gid = blockIdx.x * 256 + threadIdx.x;
  const float* src; u16* dst; int idx;
  if (gid < XN4)          { src = q; dst = oq; idx = gid; }
  else if (gid < 2*XN4)   { src = k; dst = ok; idx = gid - XN4; }
  else if (gid < 3*XN4)   { src = v; dst = ov; idx = gid - 2*XN4; }
  else {
    int g = gid - 3*XN4;
    int wsel = g >> 18;       // / WN4
    idx = g & (WN4 - 1);
    src = (wsel==0)?wq:(wsel==1)?wk:(wsel==2)?wv:wo;
    dst = (wsel==0)?owq:(wsel==1)?owk:(wsel==2)?owv:owo;
  }
  float4 val = ((const float4*)src)[idx];
  ushort4 r;
  r.x = f2bf(val.x); r.y = f2bf(val.y); r.z = f2bf(val.z); r.w = f2bf(val.w);
  ((ushort4*)dst)[idx] = r;
}

// ---------------- merged QKV projection GEMM -------------------------------
// Output cols [0,1024)=Q(RoPE), [1024,2048)=K(RoPE), [2048,3072)=V(plain).
// A matrix selected per column block (xq/xk/xv). Wcat = wq||wk||wv rows.
// Flat grid 1536, XCD-swizzled (8 row-panels per XCD).
__global__ __launch_bounds__(256)
void gemm_qkv(const u16* __restrict__ xq, const u16* __restrict__ xk,
              const u16* __restrict__ xv, const u16* __restrict__ Wcat,
              u16* __restrict__ Qh, u16* __restrict__ Kk, u16* __restrict__ Vsd){
  __shared__ __align__(16) u16 As[128*64];
  __shared__ __align__(16) u16 Bs[128*64];
  const int gblk = blockIdx.x;
  const int wid = (gblk & 7) * 192 + (gblk >> 3);
  const int bx = wid % 24, by = wid / 24;
  const int sel = bx >> 3;                        // 0=Q 1=K 2=V
  const u16* A = (sel==0) ? xq : (sel==1) ? xk : xv;
  const int tid = threadIdx.x;
  const int lane = tid & 63, w = tid >> 6;
  const int wr = w >> 1, wc = w & 1;
  const int l15 = lane & 15, lhi = lane >> 4;
  const int brow = by * 128;
  const int bcol = bx * 128;                      // global col in [0,3072)
  const int K = NSTATE;
  f32x4 acc[4][4] = {};

  for (int kt = 0; kt < K; kt += 64){
    #pragma unroll
    for (int it = 0; it < 4; ++it){
      int flat = it*4096 + tid*16;
      int row = flat >> 7, colb = flat & 127;
      gld_lds16(A + (size_t)(brow+row)*K + kt + (colb>>1), As + (flat>>1));
    }
    #pragma unroll
    for (int it = 0; it < 4; ++it){
      int flat = it*4096 + tid*16;
      int row = flat >> 7, colb = flat & 127;
      gld_lds16(Wcat + (size_t)(bcol+row)*K + kt + (colb>>1), Bs + (flat>>1));
    }
    __syncthreads();
    #pragma unroll
    for (int ks = 0; ks < 2; ++ks){
      short8 av[4], bv[4];
      #pragma unroll
      for (int i = 0; i < 4; ++i)
        av[i] = *(const short8*)&As[(wr*64 + i*16 + l15)*64 + ks*32 + lhi*8];
      #pragma unroll
      for (int j = 0; j < 4; ++j)
        bv[j] = *(const short8*)&Bs[(wc*64 + j*16 + l15)*64 + ks*32 + lhi*8];
      #pragma unroll
      for (int i = 0; i < 4; ++i)
        #pragma unroll
        for (int j = 0; j < 4; ++j)
          acc[i][j] = mfma16x16(av[i], bv[j], acc[i][j]);
    }
    __syncthreads();
  }

  const int col0 = bcol + wc*64;                  // wave's 64-col slab (one head)
  if (sel == 2){
    // V: plain bf16 [B,S,H,D] == row m, col (col0&1023)
    u16* out = Vsd;
    int c = col0 & 1023;
    #pragma unroll
    for (int i = 0; i < 4; ++i)
      #pragma unroll
      for (int reg = 0; reg < 4; ++reg){
        int m = brow + wr*64 + i*16 + lhi*4 + reg;
        u16* orow = out + (size_t)m*NSTATE + c;
        #pragma unroll
        for (int j = 0; j < 4; ++j)
          orow[j*16 + l15] = f2bf(acc[i][j][reg]);
      }
  } else {
    // Q/K: scale (incl sqrt(log2e)) + RoPE, write [B,H,S,D]
    u16* out = sel ? Kk : Qh;
    const float qk_scale = 0.4246609f;            // (1/8)^0.5 * sqrt(log2 e)
    const int head = (col0 & 1023) >> 6;
    const float invf = __powf(10000.0f, -(float)l15 * (1.0f/16.0f));
    #pragma unroll
    for (int i = 0; i < 4; ++i){
      #pragma unroll
      for (int reg = 0; reg < 4; ++reg){
        int m = brow + wr*64 + i*16 + lhi*4 + reg;
        int b = m >> 11, s = m & (NS-1);
        float sn, cs;
        __sincosf((float)s * invf, &sn, &cs);
        float x0 = acc[i][0][reg]*qk_scale;
        float x1 = acc[i][1][reg]*qk_scale;
        u16* orow = out + ((size_t)(b*NH + head)*NS + s)*ND;
        orow[ 0 + l15] = f2bf(x0*cs - x1*sn);
        orow[16 + l15] = f2bf(x1*cs + x0*sn);
        orow[32 + l15] = f2bf(acc[i][2][reg]*qk_scale);
        orow[48 + l15] = f2bf(acc[i][3][reg]*qk_scale);
      }
    }
  }
}

// ---------------- Wo GEMM: fp32 out, flat grid 512, XCD-swizzled -----------
__global__ __launch_bounds__(256)
void gemm_wo(const u16* __restrict__ A, const u16* __restrict__ Bt, float* __restrict__ out){
  __shared__ __align__(16) u16 As[128*64];
  __shared__ __align__(16) u16 Bs[128*64];
  const int gblk = blockIdx.x;
  const int wid = (gblk & 7) * 64 + (gblk >> 3);
  const int bx = wid & 7, by = wid >> 3;
  const int tid = threadIdx.x;
  const int lane = tid & 63, w = tid >> 6;
  const int wr = w >> 1, wc = w & 1;
  const int l15 = lane & 15, lhi = lane >> 4;
  const int brow = by * 128;
  const int bcol = bx * 128;
  const int K = NSTATE;
  f32x4 acc[4][4] = {};

  for (int kt = 0; kt < K; kt += 64){
    #pragma unroll
    for (int it = 0; it < 4; ++it){
      int flat = it*4096 + tid*16;
      int row = flat >> 7, colb = flat & 127;
      gld_lds16(A + (size_t)(brow+row)*K + kt + (colb>>1), As + (flat>>1));
    }
    #pragma unroll
    for (int it = 0; it < 4; ++it){
      int flat = it*4096 + tid*16;
      int row = flat >> 7, colb = flat & 127;
      gld_lds16(Bt + (size_t)(bcol+row)*K + kt + (colb>>1), Bs + (flat>>1));
    }
    __syncthreads();
    #pragma unroll
    for (int ks = 0; ks < 2; ++ks){
      short8 av[4], bv[4];
      #pragma unroll
      for (int i = 0; i < 4; ++i)
        av[i] = *(const short8*)&As[(wr*64 + i*16 + l15)*64 + ks*32 + lhi*8];
      #pragma unroll
      for (int j = 0; j < 4; ++j)
        bv[j] = *(const short8*)&Bs[(wc*64 + j*16 + l15)*64 + ks*32 + lhi*8];
      #pragma unroll
      for (int i = 0; i < 4; ++i)
        #pragma unroll
        for (int j = 0; j < 4; ++j)
          acc[i][j] = mfma16x16(av[i], bv[j], acc[i][j]);
    }
    __syncthreads();
  }
  #pragma unroll
  for (int i = 0; i < 4; ++i)
    #pragma unroll
    for (int reg = 0; reg < 4; ++reg){
      int m = brow + wr*64 + i*16 + lhi*4 + reg;
      float* orow = out + (size_t)m*NSTATE + bcol + wc*64;
      #pragma unroll
      for (int j = 0; j < 4; ++j)
        orow[j*16 + l15] = acc[i][j][reg];
    }
}

// ---------------- V [B,S,H,D] -> Vt [B,H,D,S] ----------------
__global__ __launch_bounds__(256)
void transpose_v(const u16* __restrict__ Vsd, u16* __restrict__ Vt){
  __shared__ u16 tile[64][65];
  const int bh = blockIdx.y, b = bh >> 4, h = bh & 15;
  const int s0 = blockIdx.x * 64;
  const int tid = threadIdx.x;
  #pragma unroll
  for (int p = 0; p < 2; ++p){
    int r = p*32 + (tid>>3);
    int c = (tid&7)*8;
    const u16* g = Vsd + ((size_t)((b*NS + s0 + r)*NH + h))*ND + c;
    ushort4 v0 = *(const ushort4*)g;
    ushort4 v1 = *(const ushort4*)(g+4);
    tile[r][c+0]=v0.x; tile[r][c+1]=v0.y; tile[r][c+2]=v0.z; tile[r][c+3]=v0.w;
    tile[r][c+4]=v1.x; tile[r][c+5]=v1.y; tile[r][c+6]=v1.z; tile[r][c+7]=v1.w;
  }
  __syncthreads();
  #pragma unroll
  for (int p = 0; p < 2; ++p){
    int d  = p*32 + (tid>>3);
    int sc = (tid&7)*8;
    union { u16 u[8]; uint4 v; } o;
    #pragma unroll
    for (int i = 0; i < 8; ++i) o.u[i] = tile[sc+i][d];
    *(uint4*)(Vt + ((size_t)(bh*ND + d))*NS + s0 + sc) = o.v;
  }
}

// ---------------- causal flash attention -----------------------------------
// 1-wave (64-thread) blocks, flat grid 4096: one 32-row q-tile per wave.
// XCD-swizzled (gblk&7 = XCD, each XCD owns 8 consecutive bh -> KV = 4MB L2)
// and long tiles (t=63) launch first for load balance. 16 waves/CU.
// Speculative exp2 softmax: mrun starts at 8.0 (scores << 8 in log2 domain),
// exp2 issued right after the mask; max-tree + cross-lane shfls run off the
// critical path; exact multiply-fixup if a row max ever exceeds mrun.
__global__ __launch_bounds__(64, 4)
void flash_attn(const u16* __restrict__ Q, const u16* __restrict__ Kh,
                const u16* __restrict__ Vt, u16* __restrict__ O){
  __shared__ __align__(16) u16 Pl[32*64];
  const int gblk = blockIdx.x;
  const int xcd = gblk & 7, r = gblk >> 3;
  const int t = 63 - (r >> 3);                 // long tiles first
  const int bh = xcd*8 + (r & 7);              // 8 bh per XCD
  const int qw = t*32;
  const int lane = threadIdx.x;
  const int l15 = lane & 15, lhi = lane >> 4;
  const u16* Qb = Q  + (size_t)bh*NS*ND;
  const u16* Kb = Kh + (size_t)bh*NS*ND;
  const u16* Vb = Vt + (size_t)bh*ND*NS;
  const int b = bh >> 4, h = bh & 15;

  short8 qf[2][2];
  #pragma unroll
  for (int rf = 0; rf < 2; ++rf)
    #pragma unroll
    for (int ks = 0; ks < 2; ++ks)
      qf[rf][ks] = *(const short8*)&Qb[(size_t)(qw + rf*16 + l15)*ND + ks*32 + lhi*8];

  f32x4 oacc[2][4] = {};
  float mrun[2] = {8.0f, 8.0f};
  float lrun[2] = {0.f, 0.f};
  const int kend = qw + 32;

  short8 kA[8], kB[8];
  #pragma unroll
  for (int ks = 0; ks < 2; ++ks)
    #pragma unroll
    for (int cf = 0; cf < 4; ++cf)
      kA[ks*4+cf] = *(const short8*)&Kb[(size_t)(cf*16 + l15)*ND + ks*32 + lhi*8];

  auto body = [&](int kv0, short8 (&kf)[8], short8 (&kn)[8], bool pre){
    // V loads for THIS iteration (consumed at the end; land under QK+softmax)
    short8 vf[8];
    #pragma unroll
    for (int ks = 0; ks < 2; ++ks)
      #pragma unroll
      for (int df = 0; df < 4; ++df)
        vf[ks*4+df] = *(const short8*)&Vb[(size_t)(df*16 + l15)*NS + kv0 + ks*32 + lhi*8];
    // S^T = K . Q^T : rows=k (lhi*4+reg), cols=q (l15)
    f32x4 st[2][4] = {};
    __builtin_amdgcn_s_setprio(1);
    #pragma unroll
    for (int ks = 0; ks < 2; ++ks)
      #pragma unroll
      for (int rf = 0; rf < 2; ++rf)
        #pragma unroll
        for (int cf = 0; cf < 4; ++cf)
          st[rf][cf] = mfma16x16(kf[ks*4+cf], qf[rf][ks], st[rf][cf]);
    __builtin_amdgcn_s_setprio(0);
    // prefetch K for NEXT iteration (lands under softmax + PV)
    if (pre){
      #pragma unroll
      for (int ks = 0; ks < 2; ++ks)
        #pragma unroll
        for (int cf = 0; cf < 4; ++cf)
          kn[ks*4+cf] = *(const short8*)&Kb[(size_t)(kv0 + 64 + cf*16 + l15)*ND + ks*32 + lhi*8];
    }
    // causal mask: element (k = kv0+cf*16+lhi*4+reg, q = qw+rf*16+l15)
    if (kv0 + 63 > qw){
      #pragma unroll
      for (int rf = 0; rf < 2; ++rf){
        int qq = qw + rf*16 + l15;
        #pragma unroll
        for (int cf = 0; cf < 4; ++cf){
          int kb = kv0 + cf*16 + lhi*4;
          #pragma unroll
          for (int reg = 0; reg < 4; ++reg)
            if (kb + reg > qq) st[rf][cf][reg] = -3.0e30f;
        }
      }
    }
    // in-lane row-max tree (off-critical-path check input)
    float pmax[2], rs[2];
    #pragma unroll
    for (int rf = 0; rf < 2; ++rf){
      float c4[4];
      #pragma unroll
      for (int cf = 0; cf < 4; ++cf)
        c4[cf] = fmaxf(fmaxf(st[rf][cf][0], st[rf][cf][1]),
                       fmaxf(st[rf][cf][2], st[rf][cf][3]));
      pmax[rf] = fmaxf(fmaxf(c4[0], c4[1]), fmaxf(c4[2], c4[3]));
    }
    // speculative P = exp2(S - mrun) (starts immediately; no max dependency)
    #pragma unroll
    for (int rf = 0; rf < 2; ++rf){
      #pragma unroll
      for (int cf = 0; cf < 4; ++cf)
        #pragma unroll
        for (int reg = 0; reg < 4; ++reg)
          st[rf][cf][reg] = EXP2(st[rf][cf][reg] - mrun[rf]);
      float s4[4];
      #pragma unroll
      for (int cf = 0; cf < 4; ++cf)
        s4[cf] = (st[rf][cf][0] + st[rf][cf][1]) + (st[rf][cf][2] + st[rf][cf][3]);
      rs[rf] = (s4[0] + s4[1]) + (s4[2] + s4[3]);
    }
    // cross-lane reductions (overlap with exp2 issue)
    #pragma unroll
    for (int rf = 0; rf < 2; ++rf){
      pmax[rf] = fmaxf(pmax[rf], __shfl_xor(pmax[rf], 16));
      pmax[rf] = fmaxf(pmax[rf], __shfl_xor(pmax[rf], 32));
      rs[rf] += __shfl_xor(rs[rf], 16);
      rs[rf] += __shfl_xor(rs[rf], 32);
    }
    // rare exact fixup if a row max exceeded mrun
    bool need = (pmax[0] > mrun[0]) || (pmax[1] > mrun[1]);
    if (__any(need)){
      #pragma unroll
      for (int rf = 0; rf < 2; ++rf){
        float mn = fmaxf(mrun[rf], pmax[rf]);
        float a  = EXP2(mrun[rf] - mn);
        mrun[rf] = mn;
        lrun[rf] = (lrun[rf] + rs[rf]) * a;
        #pragma unroll
        for (int cf = 0; cf < 4; ++cf)
          #pragma unroll
          for (int reg = 0; reg < 4; ++reg)
            st[rf][cf][reg] *= a;
        #pragma unroll
        for (int reg = 0; reg < 4; ++reg){
          float aT = __shfl(a, lhi*4 + reg, 64);
          #pragma unroll
          for (int df = 0; df < 4; ++df)
            oacc[rf][df][reg] *= aT;
        }
      }
    } else {
      lrun[0] += rs[0];
      lrun[1] += rs[1];
    }
    // pack P -> LDS (XOR-swizzled rows)
    #pragma unroll
    for (int rf = 0; rf < 2; ++rf){
      int row = rf*16 + l15;
      #pragma unroll
      for (int cf = 0; cf < 4; ++cf){
        uint2 pk;
        pk.x = cvtpk(st[rf][cf][0], st[rf][cf][1]);
        pk.y = cvtpk(st[rf][cf][2], st[rf][cf][3]);
        int bo = ((row<<7) + ((cf*16 + lhi*4)<<1)) ^ ((row&7)<<4);
        *(uint2*)((char*)Pl + bo) = pk;
      }
    }
    // O += P . V
    #pragma unroll
    for (int ks = 0; ks < 2; ++ks){
      short8 pf[2];
      #pragma unroll
      for (int rf = 0; rf < 2; ++rf){
        int row = rf*16 + l15;
        int bo = ((row<<7) + ((ks*32 + lhi*8)<<1)) ^ ((row&7)<<4);
        pf[rf] = *(const short8*)((const char*)Pl + bo);
      }
      __builtin_amdgcn_s_setprio(1);
      #pragma unroll
      for (int rf = 0; rf < 2; ++rf)
        #pragma unroll
        for (int df = 0; df < 4; ++df)
          oacc[rf][df] = mfma16x16(pf[rf], vf[ks*4+df], oacc[rf][df]);
      __builtin_amdgcn_s_setprio(0);
    }
  };

  int kv = 0;
  while (true){
    bool p1 = (kv + 64 < kend);
    body(kv, kA, kB, p1);
    kv += 64; if (!p1) break;
    bool p2 = (kv + 64 < kend);
    body(kv, kB, kA, p2);
    kv += 64; if (!p2) break;
  }

  // epilogue: O/l -> [B,S,H*D] bf16
  #pragma unroll
  for (int rf = 0; rf < 2; ++rf){
    float inv = 1.0f / lrun[rf];
    #pragma unroll
    for (int reg = 0; reg < 4; ++reg){
      float invT = __shfl(inv, lhi*4 + reg, 64);
      int qrow = qw + rf*16 + lhi*4 + reg;
      u16* orow = O + ((size_t)(b*NS + qrow))*NSTATE + h*ND;
      #pragma unroll
      for (int df = 0; df < 4; ++df)
        orow[df*16 + l15] = f2bf(oacc[rf][df][reg] * invT);
    }
  }
}

// ---------------------------------------------------------------------------
extern "C" void kernel_launch(void* const* d_in, const int* in_sizes, int n_in,
                              void* d_out, int out_size, void* d_ws, size_t ws_size,
                              hipStream_t stream){
  const float* q_src = (const float*)d_in[0];
  const float* k_src = (const float*)d_in[1];
  const float* v_src = (const float*)d_in[2];
  // d_in[3] = position_mask (causal, statically known) — unused
  const float* Wq = (const float*)d_in[4];
  const float* Wk = (const float*)d_in[5];
  const float* Wv = (const float*)d_in[6];
  const float* Wo = (const float*)d_in[7];

  char* ws = (char*)d_ws;
  const size_t MB = 1u << 20;
  if (ws_size < 104*MB) return;   // need 104 MB of scratch

  u16* xq   = (u16*)(ws +  0*MB);   // 16 MB  (bf16 q_src)   -> reused as Vt
  u16* xk   = (u16*)(ws + 16*MB);   // 16 MB  (bf16 k_src)   -> reused as attn out
  u16* xv   = (u16*)(ws + 32*MB);   // 16 MB  (bf16 v_src)
  u16* wq16 = (u16*)(ws + 48*MB);   //  2 MB  } contiguous => Wcat [3072][1024]
  u16* wk16 = (u16*)(ws + 50*MB);   //  2 MB  }
  u16* wv16 = (u16*)(ws + 52*MB);   //  2 MB  }
  u16* wo16 = (u16*)(ws + 54*MB);   //  2 MB
  u16* Qh   = (u16*)(ws + 56*MB);   // 16 MB  [B,H,S,D]
  u16* Kk   = (u16*)(ws + 72*MB);   // 16 MB  [B,H,S,D]
  u16* Vsd  = (u16*)(ws + 88*MB);   // 16 MB  [B,S,H,D]
  u16* Vt   = xq;                   // [B,H,D,S]  (xq dead after QKV gemm)
  u16* Oat  = xk;                   // [B,S,H*D]  (xk dead after QKV gemm)

  cvt_all<<<dim3(28672), dim3(256), 0, stream>>>(q_src, k_src, v_src, Wq, Wk, Wv, Wo,
                                                 xq, xk, xv, wq16, wk16, wv16, wo16);
  gemm_qkv<<<dim3(1536), dim3(256), 0, stream>>>(xq, xk, xv, wq16, Qh, Kk, Vsd);
  transpose_v<<<dim3(32,64), dim3(256), 0, stream>>>(Vsd, Vt);
  flash_attn<<<dim3(4096), dim3(64), 0, stream>>>(Qh, Kk, Vt, Oat);
  gemm_wo<<<dim3(512), dim3(256), 0, stream>>>(Oat, wo16, (float*)d_out);
}

// Round 6
// 341.312 us; speedup vs baseline: 2.3485x; 2.3485x over previous
//
#include <hip/hip_runtime.h>

typedef unsigned short u16;
typedef unsigned int u32;
typedef short short8 __attribute__((ext_vector_type(8)));
typedef float f32x4 __attribute__((ext_vector_type(4)));

#define NB 4
#define NS 2048
#define NSTATE 1024
#define NH 16
#define ND 64
#define NM (NB*NS)   // 8192 rows

#if __has_builtin(__builtin_amdgcn_exp2f)
#define EXP2(x) __builtin_amdgcn_exp2f(x)
#else
#define EXP2(x) __expf((x) * 0.6931471805599453f)
#endif

__device__ __forceinline__ u16 f2bf(float f){
  union { float fv; unsigned uv; } x; x.fv = f;
  unsigned r = x.uv + 0x7fffu + ((x.uv >> 16) & 1u);
  return (u16)(r >> 16);
}

__device__ __forceinline__ u32 cvtpk(float lo, float hi){
  u32 r;
  asm("v_cvt_pk_bf16_f32 %0, %1, %2" : "=v"(r) : "v"(lo), "v"(hi));
  return r;
}

__device__ __forceinline__ f32x4 mfma16x16(short8 a, short8 b, f32x4 c){
  return __builtin_amdgcn_mfma_f32_16x16x32_bf16(a, b, c, 0, 0, 0);
}

__device__ __forceinline__ void gld_lds16(const u16* g, u16* l){
  __builtin_amdgcn_global_load_lds((const __attribute__((address_space(1))) void*)g,
                                   (__attribute__((address_space(3))) void*)l, 16, 0, 0);
}

// ---------------- fp32 -> bf16 conversion for 3 activations + 4 weights ----
__global__ __launch_bounds__(256)
void cvt_all(const float* __restrict__ q, const float* __restrict__ k, const float* __restrict__ v,
             const float* __restrict__ wq, const float* __restrict__ wk,
             const float* __restrict__ wv, const float* __restrict__ wo,
             u16* oq, u16* ok, u16* ov, u16* owq, u16* owk, u16* owv, u16* owo){
  const int XN4 = (NB*NS*NSTATE)/4;   // 2097152
  const int WN4 = (NSTATE*NSTATE)/4;  // 262144
  int gid = blockIdx.x * 256 + threadIdx.x;
  const float* src; u16* dst; int idx;
  if (gid < XN4)          { src = q; dst = oq; idx = gid; }
  else if (gid < 2*XN4)   { src = k; dst = ok; idx = gid - XN4; }
  else if (gid < 3*XN4)   { src = v; dst = ov; idx = gid - 2*XN4; }
  else {
    int g = gid - 3*XN4;
    int wsel = g >> 18;       // / WN4
    idx = g & (WN4 - 1);
    src = (wsel==0)?wq:(wsel==1)?wk:(wsel==2)?wv:wo;
    dst = (wsel==0)?owq:(wsel==1)?owk:(wsel==2)?owv:owo;
  }
  float4 val = ((const float4*)src)[idx];
  ushort4 r;
  r.x = f2bf(val.x); r.y = f2bf(val.y); r.z = f2bf(val.z); r.w = f2bf(val.w);
  ((ushort4*)dst)[idx] = r;
}

// ---------------- merged QKV projection GEMM -------------------------------
// Output cols [0,1024)=Q(RoPE), [1024,2048)=K(RoPE), [2048,3072)=V(plain).
// A matrix selected per column block (xq/xk/xv). Wcat = wq||wk||wv rows.
// Flat grid 1536, XCD-swizzled (8 row-panels per XCD).
__global__ __launch_bounds__(256)
void gemm_qkv(const u16* __restrict__ xq, const u16* __restrict__ xk,
              const u16* __restrict__ xv, const u16* __restrict__ Wcat,
              u16* __restrict__ Qh, u16* __restrict__ Kk, u16* __restrict__ Vsd){
  __shared__ __align__(16) u16 As[128*64];
  __shared__ __align__(16) u16 Bs[128*64];
  const int gblk = blockIdx.x;
  const int wid = (gblk & 7) * 192 + (gblk >> 3);
  const int bx = wid % 24, by = wid / 24;
  const int sel = bx >> 3;                        // 0=Q 1=K 2=V
  const u16* A = (sel==0) ? xq : (sel==1) ? xk : xv;
  const int tid = threadIdx.x;
  const int lane = tid & 63, w = tid >> 6;
  const int wr = w >> 1, wc = w & 1;
  const int l15 = lane & 15, lhi = lane >> 4;
  const int brow = by * 128;
  const int bcol = bx * 128;                      // global col in [0,3072)
  const int K = NSTATE;
  f32x4 acc[4][4] = {};

  for (int kt = 0; kt < K; kt += 64){
    #pragma unroll
    for (int it = 0; it < 4; ++it){
      int flat = it*4096 + tid*16;
      int row = flat >> 7, colb = flat & 127;
      gld_lds16(A + (size_t)(brow+row)*K + kt + (colb>>1), As + (flat>>1));
    }
    #pragma unroll
    for (int it = 0; it < 4; ++it){
      int flat = it*4096 + tid*16;
      int row = flat >> 7, colb = flat & 127;
      gld_lds16(Wcat + (size_t)(bcol+row)*K + kt + (colb>>1), Bs + (flat>>1));
    }
    __syncthreads();
    #pragma unroll
    for (int ks = 0; ks < 2; ++ks){
      short8 av[4], bv[4];
      #pragma unroll
      for (int i = 0; i < 4; ++i)
        av[i] = *(const short8*)&As[(wr*64 + i*16 + l15)*64 + ks*32 + lhi*8];
      #pragma unroll
      for (int j = 0; j < 4; ++j)
        bv[j] = *(const short8*)&Bs[(wc*64 + j*16 + l15)*64 + ks*32 + lhi*8];
      #pragma unroll
      for (int i = 0; i < 4; ++i)
        #pragma unroll
        for (int j = 0; j < 4; ++j)
          acc[i][j] = mfma16x16(av[i], bv[j], acc[i][j]);
    }
    __syncthreads();
  }

  const int col0 = bcol + wc*64;                  // wave's 64-col slab (one head)
  if (sel == 2){
    // V: plain bf16 [B,S,H,D] == row m, col (col0&1023)
    u16* out = Vsd;
    int c = col0 & 1023;
    #pragma unroll
    for (int i = 0; i < 4; ++i)
      #pragma unroll
      for (int reg = 0; reg < 4; ++reg){
        int m = brow + wr*64 + i*16 + lhi*4 + reg;
        u16* orow = out + (size_t)m*NSTATE + c;
        #pragma unroll
        for (int j = 0; j < 4; ++j)
          orow[j*16 + l15] = f2bf(acc[i][j][reg]);
      }
  } else {
    // Q/K: scale (incl sqrt(log2e)) + RoPE, write [B,H,S,D]
    u16* out = sel ? Kk : Qh;
    const float qk_scale = 0.4246609f;            // (1/8)^0.5 * sqrt(log2 e)
    const int head = (col0 & 1023) >> 6;
    const float invf = __powf(10000.0f, -(float)l15 * (1.0f/16.0f));
    #pragma unroll
    for (int i = 0; i < 4; ++i){
      #pragma unroll
      for (int reg = 0; reg < 4; ++reg){
        int m = brow + wr*64 + i*16 + lhi*4 + reg;
        int b = m >> 11, s = m & (NS-1);
        float sn, cs;
        __sincosf((float)s * invf, &sn, &cs);
        float x0 = acc[i][0][reg]*qk_scale;
        float x1 = acc[i][1][reg]*qk_scale;
        u16* orow = out + ((size_t)(b*NH + head)*NS + s)*ND;
        orow[ 0 + l15] = f2bf(x0*cs - x1*sn);
        orow[16 + l15] = f2bf(x1*cs + x0*sn);
        orow[32 + l15] = f2bf(acc[i][2][reg]*qk_scale);
        orow[48 + l15] = f2bf(acc[i][3][reg]*qk_scale);
      }
    }
  }
}

// ---------------- Wo GEMM: fp32 out, flat grid 512, XCD-swizzled -----------
__global__ __launch_bounds__(256)
void gemm_wo(const u16* __restrict__ A, const u16* __restrict__ Bt, float* __restrict__ out){
  __shared__ __align__(16) u16 As[128*64];
  __shared__ __align__(16) u16 Bs[128*64];
  const int gblk = blockIdx.x;
  const int wid = (gblk & 7) * 64 + (gblk >> 3);
  const int bx = wid & 7, by = wid >> 3;
  const int tid = threadIdx.x;
  const int lane = tid & 63, w = tid >> 6;
  const int wr = w >> 1, wc = w & 1;
  const int l15 = lane & 15, lhi = lane >> 4;
  const int brow = by * 128;
  const int bcol = bx * 128;
  const int K = NSTATE;
  f32x4 acc[4][4] = {};

  for (int kt = 0; kt < K; kt += 64){
    #pragma unroll
    for (int it = 0; it < 4; ++it){
      int flat = it*4096 + tid*16;
      int row = flat >> 7, colb = flat & 127;
      gld_lds16(A + (size_t)(brow+row)*K + kt + (colb>>1), As + (flat>>1));
    }
    #pragma unroll
    for (int it = 0; it < 4; ++it){
      int flat = it*4096 + tid*16;
      int row = flat >> 7, colb = flat & 127;
      gld_lds16(Bt + (size_t)(bcol+row)*K + kt + (colb>>1), Bs + (flat>>1));
    }
    __syncthreads();
    #pragma unroll
    for (int ks = 0; ks < 2; ++ks){
      short8 av[4], bv[4];
      #pragma unroll
      for (int i = 0; i < 4; ++i)
        av[i] = *(const short8*)&As[(wr*64 + i*16 + l15)*64 + ks*32 + lhi*8];
      #pragma unroll
      for (int j = 0; j < 4; ++j)
        bv[j] = *(const short8*)&Bs[(wc*64 + j*16 + l15)*64 + ks*32 + lhi*8];
      #pragma unroll
      for (int i = 0; i < 4; ++i)
        #pragma unroll
        for (int j = 0; j < 4; ++j)
          acc[i][j] = mfma16x16(av[i], bv[j], acc[i][j]);
    }
    __syncthreads();
  }
  #pragma unroll
  for (int i = 0; i < 4; ++i)
    #pragma unroll
    for (int reg = 0; reg < 4; ++reg){
      int m = brow + wr*64 + i*16 + lhi*4 + reg;
      float* orow = out + (size_t)m*NSTATE + bcol + wc*64;
      #pragma unroll
      for (int j = 0; j < 4; ++j)
        orow[j*16 + l15] = acc[i][j][reg];
    }
}

// ---------------- V [B,S,H,D] -> Vt [B,H,D,S] ----------------
__global__ __launch_bounds__(256)
void transpose_v(const u16* __restrict__ Vsd, u16* __restrict__ Vt){
  __shared__ u16 tile[64][65];
  const int bh = blockIdx.y, b = bh >> 4, h = bh & 15;
  const int s0 = blockIdx.x * 64;
  const int tid = threadIdx.x;
  #pragma unroll
  for (int p = 0; p < 2; ++p){
    int r = p*32 + (tid>>3);
    int c = (tid&7)*8;
    const u16* g = Vsd + ((size_t)((b*NS + s0 + r)*NH + h))*ND + c;
    ushort4 v0 = *(const ushort4*)g;
    ushort4 v1 = *(const ushort4*)(g+4);
    tile[r][c+0]=v0.x; tile[r][c+1]=v0.y; tile[r][c+2]=v0.z; tile[r][c+3]=v0.w;
    tile[r][c+4]=v1.x; tile[r][c+5]=v1.y; tile[r][c+6]=v1.z; tile[r][c+7]=v1.w;
  }
  __syncthreads();
  #pragma unroll
  for (int p = 0; p < 2; ++p){
    int d  = p*32 + (tid>>3);
    int sc = (tid&7)*8;
    union { u16 u[8]; uint4 v; } o;
    #pragma unroll
    for (int i = 0; i < 8; ++i) o.u[i] = tile[sc+i][d];
    *(uint4*)(Vt + ((size_t)(bh*ND + d))*NS + s0 + sc) = o.v;
  }
}

// ---------------- causal flash attention -----------------------------------
// 1-wave (64-thread) blocks, flat grid 4096: one 32-row q-tile per wave.
// XCD-swizzled (gblk&7 = XCD, each XCD owns 8 consecutive bh -> KV = 4MB L2)
// and long tiles (t=63) launch first for load balance.
// launch_bounds(64,2): DO NOT raise the min-waves hint — (64,4) capped the
// kernel at 64 VGPRs and spilled ~1.4GB to scratch (R5 post-mortem).
// Speculative exp2 softmax: mrun starts at 8.0 (scores << 8 in log2 domain),
// exp2 issued right after the mask; max-tree + cross-lane shfls run off the
// critical path; exact multiply-fixup if a row max ever exceeds mrun.
__global__ __launch_bounds__(64, 2)
void flash_attn(const u16* __restrict__ Q, const u16* __restrict__ Kh,
                const u16* __restrict__ Vt, u16* __restrict__ O){
  __shared__ __align__(16) u16 Pl[32*64];
  const int gblk = blockIdx.x;
  const int xcd = gblk & 7, r = gblk >> 3;
  const int t = 63 - (r >> 3);                 // long tiles first
  const int bh = xcd*8 + (r & 7);              // 8 bh per XCD
  const int qw = t*32;
  const int lane = threadIdx.x;
  const int l15 = lane & 15, lhi = lane >> 4;
  const u16* Qb = Q  + (size_t)bh*NS*ND;
  const u16* Kb = Kh + (size_t)bh*NS*ND;
  const u16* Vb = Vt + (size_t)bh*ND*NS;
  const int b = bh >> 4, h = bh & 15;

  short8 qf[2][2];
  #pragma unroll
  for (int rf = 0; rf < 2; ++rf)
    #pragma unroll
    for (int ks = 0; ks < 2; ++ks)
      qf[rf][ks] = *(const short8*)&Qb[(size_t)(qw + rf*16 + l15)*ND + ks*32 + lhi*8];

  f32x4 oacc[2][4] = {};
  float mrun[2] = {8.0f, 8.0f};
  float lrun[2] = {0.f, 0.f};
  const int kend = qw + 32;

  short8 kA[8], kB[8];
  #pragma unroll
  for (int ks = 0; ks < 2; ++ks)
    #pragma unroll
    for (int cf = 0; cf < 4; ++cf)
      kA[ks*4+cf] = *(const short8*)&Kb[(size_t)(cf*16 + l15)*ND + ks*32 + lhi*8];

  auto body = [&](int kv0, short8 (&kf)[8], short8 (&kn)[8], bool pre){
    // V loads for THIS iteration (consumed at the end; land under QK+softmax)
    short8 vf[8];
    #pragma unroll
    for (int ks = 0; ks < 2; ++ks)
      #pragma unroll
      for (int df = 0; df < 4; ++df)
        vf[ks*4+df] = *(const short8*)&Vb[(size_t)(df*16 + l15)*NS + kv0 + ks*32 + lhi*8];
    // S^T = K . Q^T : rows=k (lhi*4+reg), cols=q (l15)
    f32x4 st[2][4] = {};
    __builtin_amdgcn_s_setprio(1);
    #pragma unroll
    for (int ks = 0; ks < 2; ++ks)
      #pragma unroll
      for (int rf = 0; rf < 2; ++rf)
        #pragma unroll
        for (int cf = 0; cf < 4; ++cf)
          st[rf][cf] = mfma16x16(kf[ks*4+cf], qf[rf][ks], st[rf][cf]);
    __builtin_amdgcn_s_setprio(0);
    // prefetch K for NEXT iteration (lands under softmax + PV)
    if (pre){
      #pragma unroll
      for (int ks = 0; ks < 2; ++ks)
        #pragma unroll
        for (int cf = 0; cf < 4; ++cf)
          kn[ks*4+cf] = *(const short8*)&Kb[(size_t)(kv0 + 64 + cf*16 + l15)*ND + ks*32 + lhi*8];
    }
    // causal mask: element (k = kv0+cf*16+lhi*4+reg, q = qw+rf*16+l15)
    if (kv0 + 63 > qw){
      #pragma unroll
      for (int rf = 0; rf < 2; ++rf){
        int qq = qw + rf*16 + l15;
        #pragma unroll
        for (int cf = 0; cf < 4; ++cf){
          int kb = kv0 + cf*16 + lhi*4;
          #pragma unroll
          for (int reg = 0; reg < 4; ++reg)
            if (kb + reg > qq) st[rf][cf][reg] = -3.0e30f;
        }
      }
    }
    // in-lane row-max tree (off-critical-path check input)
    float pmax[2], rs[2];
    #pragma unroll
    for (int rf = 0; rf < 2; ++rf){
      float c4[4];
      #pragma unroll
      for (int cf = 0; cf < 4; ++cf)
        c4[cf] = fmaxf(fmaxf(st[rf][cf][0], st[rf][cf][1]),
                       fmaxf(st[rf][cf][2], st[rf][cf][3]));
      pmax[rf] = fmaxf(fmaxf(c4[0], c4[1]), fmaxf(c4[2], c4[3]));
    }
    // speculative P = exp2(S - mrun) (starts immediately; no max dependency)
    #pragma unroll
    for (int rf = 0; rf < 2; ++rf){
      #pragma unroll
      for (int cf = 0; cf < 4; ++cf)
        #pragma unroll
        for (int reg = 0; reg < 4; ++reg)
          st[rf][cf][reg] = EXP2(st[rf][cf][reg] - mrun[rf]);
      float s4[4];
      #pragma unroll
      for (int cf = 0; cf < 4; ++cf)
        s4[cf] = (st[rf][cf][0] + st[rf][cf][1]) + (st[rf][cf][2] + st[rf][cf][3]);
      rs[rf] = (s4[0] + s4[1]) + (s4[2] + s4[3]);
    }
    // cross-lane reductions (overlap with exp2 issue)
    #pragma unroll
    for (int rf = 0; rf < 2; ++rf){
      pmax[rf] = fmaxf(pmax[rf], __shfl_xor(pmax[rf], 16));
      pmax[rf] = fmaxf(pmax[rf], __shfl_xor(pmax[rf], 32));
      rs[rf] += __shfl_xor(rs[rf], 16);
      rs[rf] += __shfl_xor(rs[rf], 32);
    }
    // rare exact fixup if a row max exceeded mrun
    bool need = (pmax[0] > mrun[0]) || (pmax[1] > mrun[1]);
    if (__any(need)){
      #pragma unroll
      for (int rf = 0; rf < 2; ++rf){
        float mn = fmaxf(mrun[rf], pmax[rf]);
        float a  = EXP2(mrun[rf] - mn);
        mrun[rf] = mn;
        lrun[rf] = (lrun[rf] + rs[rf]) * a;
        #pragma unroll
        for (int cf = 0; cf < 4; ++cf)
          #pragma unroll
          for (int reg = 0; reg < 4; ++reg)
            st[rf][cf][reg] *= a;
        #pragma unroll
        for (int reg = 0; reg < 4; ++reg){
          float aT = __shfl(a, lhi*4 + reg, 64);
          #pragma unroll
          for (int df = 0; df < 4; ++df)
            oacc[rf][df][reg] *= aT;
        }
      }
    } else {
      lrun[0] += rs[0];
      lrun[1] += rs[1];
    }
    // pack P -> LDS (XOR-swizzled rows)
    #pragma unroll
    for (int rf = 0; rf < 2; ++rf){
      int row = rf*16 + l15;
      #pragma unroll
      for (int cf = 0; cf < 4; ++cf){
        uint2 pk;
        pk.x = cvtpk(st[rf][cf][0], st[rf][cf][1]);
        pk.y = cvtpk(st[rf][cf][2], st[rf][cf][3]);
        int bo = ((row<<7) + ((cf*16 + lhi*4)<<1)) ^ ((row&7)<<4);
        *(uint2*)((char*)Pl + bo) = pk;
      }
    }
    // O += P . V
    #pragma unroll
    for (int ks = 0; ks < 2; ++ks){
      short8 pf[2];
      #pragma unroll
      for (int rf = 0; rf < 2; ++rf){
        int row = rf*16 + l15;
        int bo = ((row<<7) + ((ks*32 + lhi*8)<<1)) ^ ((row&7)<<4);
        pf[rf] = *(const short8*)((const char*)Pl + bo);
      }
      __builtin_amdgcn_s_setprio(1);
      #pragma unroll
      for (int rf = 0; rf < 2; ++rf)
        #pragma unroll
        for (int df = 0; df < 4; ++df)
          oacc[rf][df] = mfma16x16(pf[rf], vf[ks*4+df], oacc[rf][df]);
      __builtin_amdgcn_s_setprio(0);
    }
  };

  int kv = 0;
  while (true){
    bool p1 = (kv + 64 < kend);
    body(kv, kA, kB, p1);
    kv += 64; if (!p1) break;
    bool p2 = (kv + 64 < kend);
    body(kv, kB, kA, p2);
    kv += 64; if (!p2) break;
  }

  // epilogue: O/l -> [B,S,H*D] bf16
  #pragma unroll
  for (int rf = 0; rf < 2; ++rf){
    float inv = 1.0f / lrun[rf];
    #pragma unroll
    for (int reg = 0; reg < 4; ++reg){
      float invT = __shfl(inv, lhi*4 + reg, 64);
      int qrow = qw + rf*16 + lhi*4 + reg;
      u16* orow = O + ((size_t)(b*NS + qrow))*NSTATE + h*ND;
      #pragma unroll
      for (int df = 0; df < 4; ++df)
        orow[df*16 + l15] = f2bf(oacc[rf][df][reg] * invT);
    }
  }
}

// ---------------------------------------------------------------------------
extern "C" void kernel_launch(void* const* d_in, const int* in_sizes, int n_in,
                              void* d_out, int out_size, void* d_ws, size_t ws_size,
                              hipStream_t stream){
  const float* q_src = (const float*)d_in[0];
  const float* k_src = (const float*)d_in[1];
  const float* v_src = (const float*)d_in[2];
  // d_in[3] = position_mask (causal, statically known) — unused
  const float* Wq = (const float*)d_in[4];
  const float* Wk = (const float*)d_in[5];
  const float* Wv = (const float*)d_in[6];
  const float* Wo = (const float*)d_in[7];

  char* ws = (char*)d_ws;
  const size_t MB = 1u << 20;
  if (ws_size < 104*MB) return;   // need 104 MB of scratch

  u16* xq   = (u16*)(ws +  0*MB);   // 16 MB  (bf16 q_src)   -> reused as Vt
  u16* xk   = (u16*)(ws + 16*MB);   // 16 MB  (bf16 k_src)   -> reused as attn out
  u16* xv   = (u16*)(ws + 32*MB);   // 16 MB  (bf16 v_src)
  u16* wq16 = (u16*)(ws + 48*MB);   //  2 MB  } contiguous => Wcat [3072][1024]
  u16* wk16 = (u16*)(ws + 50*MB);   //  2 MB  }
  u16* wv16 = (u16*)(ws + 52*MB);   //  2 MB  }
  u16* wo16 = (u16*)(ws + 54*MB);   //  2 MB
  u16* Qh   = (u16*)(ws + 56*MB);   // 16 MB  [B,H,S,D]
  u16* Kk   = (u16*)(ws + 72*MB);   // 16 MB  [B,H,S,D]
  u16* Vsd  = (u16*)(ws + 88*MB);   // 16 MB  [B,S,H,D]
  u16* Vt   = xq;                   // [B,H,D,S]  (xq dead after QKV gemm)
  u16* Oat  = xk;                   // [B,S,H*D]  (xk dead after QKV gemm)

  cvt_all<<<dim3(28672), dim3(256), 0, stream>>>(q_src, k_src, v_src, Wq, Wk, Wv, Wo,
                                                 xq, xk, xv, wq16, wk16, wv16, wo16);
  gemm_qkv<<<dim3(1536), dim3(256), 0, stream>>>(xq, xk, xv, wq16, Qh, Kk, Vsd);
  transpose_v<<<dim3(32,64), dim3(256), 0, stream>>>(Vsd, Vt);
  flash_attn<<<dim3(4096), dim3(64), 0, stream>>>(Qh, Kk, Vt, Oat);
  gemm_wo<<<dim3(512), dim3(256), 0, stream>>>(Oat, wo16, (float*)d_out);
}

// Round 7
// 263.825 us; speedup vs baseline: 3.0382x; 1.2937x over previous
//
#include <hip/hip_runtime.h>

typedef unsigned short u16;
typedef unsigned int u32;
typedef short short8 __attribute__((ext_vector_type(8)));
typedef float f32x4 __attribute__((ext_vector_type(4)));

#define NB 4
#define NS 2048
#define NSTATE 1024
#define NH 16
#define ND 64
#define NM (NB*NS)   // 8192 rows

#if __has_builtin(__builtin_amdgcn_exp2f)
#define EXP2(x) __builtin_amdgcn_exp2f(x)
#else
#define EXP2(x) __expf((x) * 0.6931471805599453f)
#endif

__device__ __forceinline__ u16 f2bf(float f){
  union { float fv; unsigned uv; } x; x.fv = f;
  unsigned r = x.uv + 0x7fffu + ((x.uv >> 16) & 1u);
  return (u16)(r >> 16);
}

__device__ __forceinline__ u32 cvtpk(float lo, float hi){
  u32 r;
  asm("v_cvt_pk_bf16_f32 %0, %1, %2" : "=v"(r) : "v"(lo), "v"(hi));
  return r;
}

__device__ __forceinline__ f32x4 mfma16x16(short8 a, short8 b, f32x4 c){
  return __builtin_amdgcn_mfma_f32_16x16x32_bf16(a, b, c, 0, 0, 0);
}

__device__ __forceinline__ void gld_lds16(const u16* g, u16* l){
  __builtin_amdgcn_global_load_lds((const __attribute__((address_space(1))) void*)g,
                                   (__attribute__((address_space(3))) void*)l, 16, 0, 0);
}

// ---------------- fp32 -> bf16 conversion for 3 activations + 4 weights ----
__global__ __launch_bounds__(256)
void cvt_all(const float* __restrict__ q, const float* __restrict__ k, const float* __restrict__ v,
             const float* __restrict__ wq, const float* __restrict__ wk,
             const float* __restrict__ wv, const float* __restrict__ wo,
             u16* oq, u16* ok, u16* ov, u16* owq, u16* owk, u16* owv, u16* owo){
  const int XN4 = (NB*NS*NSTATE)/4;   // 2097152
  const int WN4 = (NSTATE*NSTATE)/4;  // 262144
  int gid = blockIdx.x * 256 + threadIdx.x;
  const float* src; u16* dst; int idx;
  if (gid < XN4)          { src = q; dst = oq; idx = gid; }
  else if (gid < 2*XN4)   { src = k; dst = ok; idx = gid - XN4; }
  else if (gid < 3*XN4)   { src = v; dst = ov; idx = gid - 2*XN4; }
  else {
    int g = gid - 3*XN4;
    int wsel = g >> 18;       // / WN4
    idx = g & (WN4 - 1);
    src = (wsel==0)?wq:(wsel==1)?wk:(wsel==2)?wv:wo;
    dst = (wsel==0)?owq:(wsel==1)?owk:(wsel==2)?owv:owo;
  }
  float4 val = ((const float4*)src)[idx];
  ushort4 r;
  r.x = f2bf(val.x); r.y = f2bf(val.y); r.z = f2bf(val.z); r.w = f2bf(val.w);
  ((ushort4*)dst)[idx] = r;
}

// ---------------- merged QKV projection GEMM -------------------------------
// Output cols [0,1024)=Q(RoPE), [1024,2048)=K(RoPE), [2048,3072)=V (written
// DIRECTLY transposed to Vt[B,H,D,S] from the fragment layout: the 4 acc regs
// of a fragment are 4 consecutive s at fixed d -> packed uint2 stores).
// A matrix selected per column block (xq/xk/xv). Wcat = wq||wk||wv rows.
// Flat grid 1536, XCD-swizzled (8 row-panels per XCD).
__global__ __launch_bounds__(256)
void gemm_qkv(const u16* __restrict__ xq, const u16* __restrict__ xk,
              const u16* __restrict__ xv, const u16* __restrict__ Wcat,
              u16* __restrict__ Qh, u16* __restrict__ Kk, u16* __restrict__ Vt){
  __shared__ __align__(16) u16 As[128*64];
  __shared__ __align__(16) u16 Bs[128*64];
  const int gblk = blockIdx.x;
  const int wid = (gblk & 7) * 192 + (gblk >> 3);
  const int bx = wid % 24, by = wid / 24;
  const int sel = bx >> 3;                        // 0=Q 1=K 2=V
  const u16* A = (sel==0) ? xq : (sel==1) ? xk : xv;
  const int tid = threadIdx.x;
  const int lane = tid & 63, w = tid >> 6;
  const int wr = w >> 1, wc = w & 1;
  const int l15 = lane & 15, lhi = lane >> 4;
  const int brow = by * 128;
  const int bcol = bx * 128;                      // global col in [0,3072)
  const int K = NSTATE;
  f32x4 acc[4][4] = {};

  for (int kt = 0; kt < K; kt += 64){
    #pragma unroll
    for (int it = 0; it < 4; ++it){
      int flat = it*4096 + tid*16;
      int row = flat >> 7, colb = flat & 127;
      gld_lds16(A + (size_t)(brow+row)*K + kt + (colb>>1), As + (flat>>1));
    }
    #pragma unroll
    for (int it = 0; it < 4; ++it){
      int flat = it*4096 + tid*16;
      int row = flat >> 7, colb = flat & 127;
      gld_lds16(Wcat + (size_t)(bcol+row)*K + kt + (colb>>1), Bs + (flat>>1));
    }
    __syncthreads();
    #pragma unroll
    for (int ks = 0; ks < 2; ++ks){
      short8 av[4], bv[4];
      #pragma unroll
      for (int i = 0; i < 4; ++i)
        av[i] = *(const short8*)&As[(wr*64 + i*16 + l15)*64 + ks*32 + lhi*8];
      #pragma unroll
      for (int j = 0; j < 4; ++j)
        bv[j] = *(const short8*)&Bs[(wc*64 + j*16 + l15)*64 + ks*32 + lhi*8];
      #pragma unroll
      for (int i = 0; i < 4; ++i)
        #pragma unroll
        for (int j = 0; j < 4; ++j)
          acc[i][j] = mfma16x16(av[i], bv[j], acc[i][j]);
    }
    __syncthreads();
  }

  const int col0 = bcol + wc*64;                  // wave's 64-col slab (one head)
  if (sel == 2){
    // V -> Vt[B,H,D,S] directly: d = j*16+l15, s0 = (m of reg 0) & 2047.
    const int head = (col0 & 1023) >> 6;
    #pragma unroll
    for (int i = 0; i < 4; ++i){
      int m0 = brow + wr*64 + i*16 + lhi*4;       // reg 0 row (4 consecutive s)
      int b = m0 >> 11, s0 = m0 & (NS-1);
      u16* obase = Vt + ((size_t)((b*NH + head)*ND))*NS + s0;
      #pragma unroll
      for (int j = 0; j < 4; ++j){
        int d = j*16 + l15;
        uint2 pk;
        pk.x = cvtpk(acc[i][j][0], acc[i][j][1]);
        pk.y = cvtpk(acc[i][j][2], acc[i][j][3]);
        *(uint2*)(obase + (size_t)d*NS) = pk;
      }
    }
  } else {
    // Q/K: scale (incl sqrt(log2e)) + RoPE, write [B,H,S,D]
    u16* out = sel ? Kk : Qh;
    const float qk_scale = 0.4246609f;            // (1/8)^0.5 * sqrt(log2 e)
    const int head = (col0 & 1023) >> 6;
    const float invf = __powf(10000.0f, -(float)l15 * (1.0f/16.0f));
    #pragma unroll
    for (int i = 0; i < 4; ++i){
      #pragma unroll
      for (int reg = 0; reg < 4; ++reg){
        int m = brow + wr*64 + i*16 + lhi*4 + reg;
        int b = m >> 11, s = m & (NS-1);
        float sn, cs;
        __sincosf((float)s * invf, &sn, &cs);
        float x0 = acc[i][0][reg]*qk_scale;
        float x1 = acc[i][1][reg]*qk_scale;
        u16* orow = out + ((size_t)(b*NH + head)*NS + s)*ND;
        orow[ 0 + l15] = f2bf(x0*cs - x1*sn);
        orow[16 + l15] = f2bf(x1*cs + x0*sn);
        orow[32 + l15] = f2bf(acc[i][2][reg]*qk_scale);
        orow[48 + l15] = f2bf(acc[i][3][reg]*qk_scale);
      }
    }
  }
}

// ---------------- Wo GEMM: fp32 out, flat grid 512, XCD-swizzled -----------
__global__ __launch_bounds__(256)
void gemm_wo(const u16* __restrict__ A, const u16* __restrict__ Bt, float* __restrict__ out){
  __shared__ __align__(16) u16 As[128*64];
  __shared__ __align__(16) u16 Bs[128*64];
  const int gblk = blockIdx.x;
  const int wid = (gblk & 7) * 64 + (gblk >> 3);
  const int bx = wid & 7, by = wid >> 3;
  const int tid = threadIdx.x;
  const int lane = tid & 63, w = tid >> 6;
  const int wr = w >> 1, wc = w & 1;
  const int l15 = lane & 15, lhi = lane >> 4;
  const int brow = by * 128;
  const int bcol = bx * 128;
  const int K = NSTATE;
  f32x4 acc[4][4] = {};

  for (int kt = 0; kt < K; kt += 64){
    #pragma unroll
    for (int it = 0; it < 4; ++it){
      int flat = it*4096 + tid*16;
      int row = flat >> 7, colb = flat & 127;
      gld_lds16(A + (size_t)(brow+row)*K + kt + (colb>>1), As + (flat>>1));
    }
    #pragma unroll
    for (int it = 0; it < 4; ++it){
      int flat = it*4096 + tid*16;
      int row = flat >> 7, colb = flat & 127;
      gld_lds16(Bt + (size_t)(bcol+row)*K + kt + (colb>>1), Bs + (flat>>1));
    }
    __syncthreads();
    #pragma unroll
    for (int ks = 0; ks < 2; ++ks){
      short8 av[4], bv[4];
      #pragma unroll
      for (int i = 0; i < 4; ++i)
        av[i] = *(const short8*)&As[(wr*64 + i*16 + l15)*64 + ks*32 + lhi*8];
      #pragma unroll
      for (int j = 0; j < 4; ++j)
        bv[j] = *(const short8*)&Bs[(wc*64 + j*16 + l15)*64 + ks*32 + lhi*8];
      #pragma unroll
      for (int i = 0; i < 4; ++i)
        #pragma unroll
        for (int j = 0; j < 4; ++j)
          acc[i][j] = mfma16x16(av[i], bv[j], acc[i][j]);
    }
    __syncthreads();
  }
  #pragma unroll
  for (int i = 0; i < 4; ++i)
    #pragma unroll
    for (int reg = 0; reg < 4; ++reg){
      int m = brow + wr*64 + i*16 + lhi*4 + reg;
      float* orow = out + (size_t)m*NSTATE + bcol + wc*64;
      #pragma unroll
      for (int j = 0; j < 4; ++j)
        orow[j*16 + l15] = acc[i][j][reg];
    }
}

// ---------------- causal flash attention -----------------------------------
// 1-wave (64-thread) blocks, flat grid 4096: one 32-row q-tile per wave.
// XCD-swizzled (gblk&7 = XCD, each XCD owns 8 consecutive bh -> KV = 4MB L2)
// and long tiles (t=63) launch first for load balance.
// launch_bounds(64) with NO min-waves hint: the kernel's live set is ~190
// VGPRs; any cap <= 128 spills (R5: 64-cap -> 1.4GB scratch, R6: 128-cap ->
// 110MB scratch). Uncapped: ~200 VGPR, 2 waves/SIMD, zero spill.
// Speculative exp2 softmax: mrun starts at 8.0, exp2 issued right after the
// mask; max/sum cross-lane shfls off the critical path; exact fixup if ever
// a row max exceeds mrun.
__global__ __launch_bounds__(64)
void flash_attn(const u16* __restrict__ Q, const u16* __restrict__ Kh,
                const u16* __restrict__ Vt, u16* __restrict__ O){
  __shared__ __align__(16) u16 Pl[32*64];
  const int gblk = blockIdx.x;
  const int xcd = gblk & 7, r = gblk >> 3;
  const int t = 63 - (r >> 3);                 // long tiles first
  const int bh = xcd*8 + (r & 7);              // 8 bh per XCD
  const int qw = t*32;
  const int lane = threadIdx.x;
  const int l15 = lane & 15, lhi = lane >> 4;
  const u16* Qb = Q  + (size_t)bh*NS*ND;
  const u16* Kb = Kh + (size_t)bh*NS*ND;
  const u16* Vb = Vt + (size_t)bh*ND*NS;
  const int b = bh >> 4, h = bh & 15;

  short8 qf[2][2];
  #pragma unroll
  for (int rf = 0; rf < 2; ++rf)
    #pragma unroll
    for (int ks = 0; ks < 2; ++ks)
      qf[rf][ks] = *(const short8*)&Qb[(size_t)(qw + rf*16 + l15)*ND + ks*32 + lhi*8];

  f32x4 oacc[2][4] = {};
  float mrun[2] = {8.0f, 8.0f};
  float lrun[2] = {0.f, 0.f};
  const int kend = qw + 32;

  short8 kA[8], kB[8];
  #pragma unroll
  for (int ks = 0; ks < 2; ++ks)
    #pragma unroll
    for (int cf = 0; cf < 4; ++cf)
      kA[ks*4+cf] = *(const short8*)&Kb[(size_t)(cf*16 + l15)*ND + ks*32 + lhi*8];

  auto body = [&](int kv0, short8 (&kf)[8], short8 (&kn)[8], bool pre){
    // V loads for THIS iteration (consumed at the end; land under QK+softmax)
    short8 vf[8];
    #pragma unroll
    for (int ks = 0; ks < 2; ++ks)
      #pragma unroll
      for (int df = 0; df < 4; ++df)
        vf[ks*4+df] = *(const short8*)&Vb[(size_t)(df*16 + l15)*NS + kv0 + ks*32 + lhi*8];
    // S^T = K . Q^T : rows=k (lhi*4+reg), cols=q (l15)
    f32x4 st[2][4] = {};
    __builtin_amdgcn_s_setprio(1);
    #pragma unroll
    for (int ks = 0; ks < 2; ++ks)
      #pragma unroll
      for (int rf = 0; rf < 2; ++rf)
        #pragma unroll
        for (int cf = 0; cf < 4; ++cf)
          st[rf][cf] = mfma16x16(kf[ks*4+cf], qf[rf][ks], st[rf][cf]);
    __builtin_amdgcn_s_setprio(0);
    // prefetch K for NEXT iteration (lands under softmax + PV)
    if (pre){
      #pragma unroll
      for (int ks = 0; ks < 2; ++ks)
        #pragma unroll
        for (int cf = 0; cf < 4; ++cf)
          kn[ks*4+cf] = *(const short8*)&Kb[(size_t)(kv0 + 64 + cf*16 + l15)*ND + ks*32 + lhi*8];
    }
    // causal mask: element (k = kv0+cf*16+lhi*4+reg, q = qw+rf*16+l15)
    if (kv0 + 63 > qw){
      #pragma unroll
      for (int rf = 0; rf < 2; ++rf){
        int qq = qw + rf*16 + l15;
        #pragma unroll
        for (int cf = 0; cf < 4; ++cf){
          int kb = kv0 + cf*16 + lhi*4;
          #pragma unroll
          for (int reg = 0; reg < 4; ++reg)
            if (kb + reg > qq) st[rf][cf][reg] = -3.0e30f;
        }
      }
    }
    // in-lane row-max tree (off-critical-path check input)
    float pmax[2], rs[2];
    #pragma unroll
    for (int rf = 0; rf < 2; ++rf){
      float c4[4];
      #pragma unroll
      for (int cf = 0; cf < 4; ++cf)
        c4[cf] = fmaxf(fmaxf(st[rf][cf][0], st[rf][cf][1]),
                       fmaxf(st[rf][cf][2], st[rf][cf][3]));
      pmax[rf] = fmaxf(fmaxf(c4[0], c4[1]), fmaxf(c4[2], c4[3]));
    }
    // speculative P = exp2(S - mrun) (starts immediately; no max dependency)
    #pragma unroll
    for (int rf = 0; rf < 2; ++rf){
      #pragma unroll
      for (int cf = 0; cf < 4; ++cf)
        #pragma unroll
        for (int reg = 0; reg < 4; ++reg)
          st[rf][cf][reg] = EXP2(st[rf][cf][reg] - mrun[rf]);
      float s4[4];
      #pragma unroll
      for (int cf = 0; cf < 4; ++cf)
        s4[cf] = (st[rf][cf][0] + st[rf][cf][1]) + (st[rf][cf][2] + st[rf][cf][3]);
      rs[rf] = (s4[0] + s4[1]) + (s4[2] + s4[3]);
    }
    // cross-lane reductions (overlap with exp2 issue)
    #pragma unroll
    for (int rf = 0; rf < 2; ++rf){
      pmax[rf] = fmaxf(pmax[rf], __shfl_xor(pmax[rf], 16));
      pmax[rf] = fmaxf(pmax[rf], __shfl_xor(pmax[rf], 32));
      rs[rf] += __shfl_xor(rs[rf], 16);
      rs[rf] += __shfl_xor(rs[rf], 32);
    }
    // rare exact fixup if a row max exceeded mrun
    bool need = (pmax[0] > mrun[0]) || (pmax[1] > mrun[1]);
    if (__any(need)){
      #pragma unroll
      for (int rf = 0; rf < 2; ++rf){
        float mn = fmaxf(mrun[rf], pmax[rf]);
        float a  = EXP2(mrun[rf] - mn);
        mrun[rf] = mn;
        lrun[rf] = (lrun[rf] + rs[rf]) * a;
        #pragma unroll
        for (int cf = 0; cf < 4; ++cf)
          #pragma unroll
          for (int reg = 0; reg < 4; ++reg)
            st[rf][cf][reg] *= a;
        #pragma unroll
        for (int reg = 0; reg < 4; ++reg){
          float aT = __shfl(a, lhi*4 + reg, 64);
          #pragma unroll
          for (int df = 0; df < 4; ++df)
            oacc[rf][df][reg] *= aT;
        }
      }
    } else {
      lrun[0] += rs[0];
      lrun[1] += rs[1];
    }
    // pack P -> LDS (XOR-swizzled rows)
    #pragma unroll
    for (int rf = 0; rf < 2; ++rf){
      int row = rf*16 + l15;
      #pragma unroll
      for (int cf = 0; cf < 4; ++cf){
        uint2 pk;
        pk.x = cvtpk(st[rf][cf][0], st[rf][cf][1]);
        pk.y = cvtpk(st[rf][cf][2], st[rf][cf][3]);
        int bo = ((row<<7) + ((cf*16 + lhi*4)<<1)) ^ ((row&7)<<4);
        *(uint2*)((char*)Pl + bo) = pk;
      }
    }
    // O += P . V
    #pragma unroll
    for (int ks = 0; ks < 2; ++ks){
      short8 pf[2];
      #pragma unroll
      for (int rf = 0; rf < 2; ++rf){
        int row = rf*16 + l15;
        int bo = ((row<<7) + ((ks*32 + lhi*8)<<1)) ^ ((row&7)<<4);
        pf[rf] = *(const short8*)((const char*)Pl + bo);
      }
      __builtin_amdgcn_s_setprio(1);
      #pragma unroll
      for (int rf = 0; rf < 2; ++rf)
        #pragma unroll
        for (int df = 0; df < 4; ++df)
          oacc[rf][df] = mfma16x16(pf[rf], vf[ks*4+df], oacc[rf][df]);
      __builtin_amdgcn_s_setprio(0);
    }
  };

  int kv = 0;
  while (true){
    bool p1 = (kv + 64 < kend);
    body(kv, kA, kB, p1);
    kv += 64; if (!p1) break;
    bool p2 = (kv + 64 < kend);
    body(kv, kB, kA, p2);
    kv += 64; if (!p2) break;
  }

  // epilogue: O/l -> [B,S,H*D] bf16
  #pragma unroll
  for (int rf = 0; rf < 2; ++rf){
    float inv = 1.0f / lrun[rf];
    #pragma unroll
    for (int reg = 0; reg < 4; ++reg){
      float invT = __shfl(inv, lhi*4 + reg, 64);
      int qrow = qw + rf*16 + lhi*4 + reg;
      u16* orow = O + ((size_t)(b*NS + qrow))*NSTATE + h*ND;
      #pragma unroll
      for (int df = 0; df < 4; ++df)
        orow[df*16 + l15] = f2bf(oacc[rf][df][reg] * invT);
    }
  }
}

// ---------------------------------------------------------------------------
extern "C" void kernel_launch(void* const* d_in, const int* in_sizes, int n_in,
                              void* d_out, int out_size, void* d_ws, size_t ws_size,
                              hipStream_t stream){
  const float* q_src = (const float*)d_in[0];
  const float* k_src = (const float*)d_in[1];
  const float* v_src = (const float*)d_in[2];
  // d_in[3] = position_mask (causal, statically known) — unused
  const float* Wq = (const float*)d_in[4];
  const float* Wk = (const float*)d_in[5];
  const float* Wv = (const float*)d_in[6];
  const float* Wo = (const float*)d_in[7];

  char* ws = (char*)d_ws;
  const size_t MB = 1u << 20;
  if (ws_size < 104*MB) return;   // need 104 MB of scratch

  u16* xq   = (u16*)(ws +  0*MB);   // 16 MB  (bf16 q_src)
  u16* xk   = (u16*)(ws + 16*MB);   // 16 MB  (bf16 k_src)   -> reused as attn out
  u16* xv   = (u16*)(ws + 32*MB);   // 16 MB  (bf16 v_src)
  u16* wq16 = (u16*)(ws + 48*MB);   //  2 MB  } contiguous => Wcat [3072][1024]
  u16* wk16 = (u16*)(ws + 50*MB);   //  2 MB  }
  u16* wv16 = (u16*)(ws + 52*MB);   //  2 MB  }
  u16* wo16 = (u16*)(ws + 54*MB);   //  2 MB
  u16* Qh   = (u16*)(ws + 56*MB);   // 16 MB  [B,H,S,D]
  u16* Kk   = (u16*)(ws + 72*MB);   // 16 MB  [B,H,S,D]
  u16* Vt   = (u16*)(ws + 88*MB);   // 16 MB  [B,H,D,S]  (direct from gemm_qkv)
  u16* Oat  = xk;                   // [B,S,H*D]  (xk dead after QKV gemm)

  cvt_all<<<dim3(28672), dim3(256), 0, stream>>>(q_src, k_src, v_src, Wq, Wk, Wv, Wo,
                                                 xq, xk, xv, wq16, wk16, wv16, wo16);
  gemm_qkv<<<dim3(1536), dim3(256), 0, stream>>>(xq, xk, xv, wq16, Qh, Kk, Vt);
  flash_attn<<<dim3(4096), dim3(64), 0, stream>>>(Qh, Kk, Vt, Oat);
  gemm_wo<<<dim3(512), dim3(256), 0, stream>>>(Oat, wo16, (float*)d_out);
}

// Round 8
// 259.662 us; speedup vs baseline: 3.0869x; 1.0160x over previous
//
#include <hip/hip_runtime.h>

typedef unsigned short u16;
typedef unsigned int u32;
typedef short short8 __attribute__((ext_vector_type(8)));
typedef float f32x4 __attribute__((ext_vector_type(4)));

#define NB 4
#define NS 2048
#define NSTATE 1024
#define NH 16
#define ND 64
#define NM (NB*NS)   // 8192 rows

#if __has_builtin(__builtin_amdgcn_exp2f)
#define EXP2(x) __builtin_amdgcn_exp2f(x)
#else
#define EXP2(x) __expf((x) * 0.6931471805599453f)
#endif

__device__ __forceinline__ u16 f2bf(float f){
  union { float fv; unsigned uv; } x; x.fv = f;
  unsigned r = x.uv + 0x7fffu + ((x.uv >> 16) & 1u);
  return (u16)(r >> 16);
}

__device__ __forceinline__ u32 cvtpk(float lo, float hi){
  u32 r;
  asm("v_cvt_pk_bf16_f32 %0, %1, %2" : "=v"(r) : "v"(lo), "v"(hi));
  return r;
}

__device__ __forceinline__ f32x4 mfma16x16(short8 a, short8 b, f32x4 c){
  return __builtin_amdgcn_mfma_f32_16x16x32_bf16(a, b, c, 0, 0, 0);
}

__device__ __forceinline__ void gld_lds16(const u16* g, u16* l){
  __builtin_amdgcn_global_load_lds((const __attribute__((address_space(1))) void*)g,
                                   (__attribute__((address_space(3))) void*)l, 16, 0, 0);
}

// ---------------- fp32 -> bf16 conversion for 3 activations + 4 weights ----
__global__ __launch_bounds__(256)
void cvt_all(const float* __restrict__ q, const float* __restrict__ k, const float* __restrict__ v,
             const float* __restrict__ wq, const float* __restrict__ wk,
             const float* __restrict__ wv, const float* __restrict__ wo,
             u16* oq, u16* ok, u16* ov, u16* owq, u16* owk, u16* owv, u16* owo){
  const int XN4 = (NB*NS*NSTATE)/4;   // 2097152
  const int WN4 = (NSTATE*NSTATE)/4;  // 262144
  int gid = blockIdx.x * 256 + threadIdx.x;
  const float* src; u16* dst; int idx;
  if (gid < XN4)          { src = q; dst = oq; idx = gid; }
  else if (gid < 2*XN4)   { src = k; dst = ok; idx = gid - XN4; }
  else if (gid < 3*XN4)   { src = v; dst = ov; idx = gid - 2*XN4; }
  else {
    int g = gid - 3*XN4;
    int wsel = g >> 18;       // / WN4
    idx = g & (WN4 - 1);
    src = (wsel==0)?wq:(wsel==1)?wk:(wsel==2)?wv:wo;
    dst = (wsel==0)?owq:(wsel==1)?owk:(wsel==2)?owv:owo;
  }
  float4 val = ((const float4*)src)[idx];
  ushort4 r;
  r.x = f2bf(val.x); r.y = f2bf(val.y); r.z = f2bf(val.z); r.w = f2bf(val.w);
  ((ushort4*)dst)[idx] = r;
}

// ---------------- merged QKV projection GEMM -------------------------------
// Output cols [0,1024)=Q(RoPE), [1024,2048)=K(RoPE), [2048,3072)=V (written
// DIRECTLY transposed to Vt[B,H,D,S] from the fragment layout).
// Flat grid 1536, XCD-swizzled (8 row-panels per XCD).
__global__ __launch_bounds__(256)
void gemm_qkv(const u16* __restrict__ xq, const u16* __restrict__ xk,
              const u16* __restrict__ xv, const u16* __restrict__ Wcat,
              u16* __restrict__ Qh, u16* __restrict__ Kk, u16* __restrict__ Vt){
  __shared__ __align__(16) u16 As[128*64];
  __shared__ __align__(16) u16 Bs[128*64];
  const int gblk = blockIdx.x;
  const int wid = (gblk & 7) * 192 + (gblk >> 3);
  const int bx = wid % 24, by = wid / 24;
  const int sel = bx >> 3;                        // 0=Q 1=K 2=V
  const u16* A = (sel==0) ? xq : (sel==1) ? xk : xv;
  const int tid = threadIdx.x;
  const int lane = tid & 63, w = tid >> 6;
  const int wr = w >> 1, wc = w & 1;
  const int l15 = lane & 15, lhi = lane >> 4;
  const int brow = by * 128;
  const int bcol = bx * 128;                      // global col in [0,3072)
  const int K = NSTATE;
  f32x4 acc[4][4] = {};

  for (int kt = 0; kt < K; kt += 64){
    #pragma unroll
    for (int it = 0; it < 4; ++it){
      int flat = it*4096 + tid*16;
      int row = flat >> 7, colb = flat & 127;
      gld_lds16(A + (size_t)(brow+row)*K + kt + (colb>>1), As + (flat>>1));
    }
    #pragma unroll
    for (int it = 0; it < 4; ++it){
      int flat = it*4096 + tid*16;
      int row = flat >> 7, colb = flat & 127;
      gld_lds16(Wcat + (size_t)(bcol+row)*K + kt + (colb>>1), Bs + (flat>>1));
    }
    __syncthreads();
    #pragma unroll
    for (int ks = 0; ks < 2; ++ks){
      short8 av[4], bv[4];
      #pragma unroll
      for (int i = 0; i < 4; ++i)
        av[i] = *(const short8*)&As[(wr*64 + i*16 + l15)*64 + ks*32 + lhi*8];
      #pragma unroll
      for (int j = 0; j < 4; ++j)
        bv[j] = *(const short8*)&Bs[(wc*64 + j*16 + l15)*64 + ks*32 + lhi*8];
      #pragma unroll
      for (int i = 0; i < 4; ++i)
        #pragma unroll
        for (int j = 0; j < 4; ++j)
          acc[i][j] = mfma16x16(av[i], bv[j], acc[i][j]);
    }
    __syncthreads();
  }

  const int col0 = bcol + wc*64;                  // wave's 64-col slab (one head)
  if (sel == 2){
    // V -> Vt[B,H,D,S] directly: d = j*16+l15, s0 = (m of reg 0) & 2047.
    const int head = (col0 & 1023) >> 6;
    #pragma unroll
    for (int i = 0; i < 4; ++i){
      int m0 = brow + wr*64 + i*16 + lhi*4;       // reg 0 row (4 consecutive s)
      int b = m0 >> 11, s0 = m0 & (NS-1);
      u16* obase = Vt + ((size_t)((b*NH + head)*ND))*NS + s0;
      #pragma unroll
      for (int j = 0; j < 4; ++j){
        int d = j*16 + l15;
        uint2 pk;
        pk.x = cvtpk(acc[i][j][0], acc[i][j][1]);
        pk.y = cvtpk(acc[i][j][2], acc[i][j][3]);
        *(uint2*)(obase + (size_t)d*NS) = pk;
      }
    }
  } else {
    // Q/K: scale (incl sqrt(log2e)) + RoPE, write [B,H,S,D]
    u16* out = sel ? Kk : Qh;
    const float qk_scale = 0.4246609f;            // (1/8)^0.5 * sqrt(log2 e)
    const int head = (col0 & 1023) >> 6;
    const float invf = __powf(10000.0f, -(float)l15 * (1.0f/16.0f));
    #pragma unroll
    for (int i = 0; i < 4; ++i){
      #pragma unroll
      for (int reg = 0; reg < 4; ++reg){
        int m = brow + wr*64 + i*16 + lhi*4 + reg;
        int b = m >> 11, s = m & (NS-1);
        float sn, cs;
        __sincosf((float)s * invf, &sn, &cs);
        float x0 = acc[i][0][reg]*qk_scale;
        float x1 = acc[i][1][reg]*qk_scale;
        u16* orow = out + ((size_t)(b*NH + head)*NS + s)*ND;
        orow[ 0 + l15] = f2bf(x0*cs - x1*sn);
        orow[16 + l15] = f2bf(x1*cs + x0*sn);
        orow[32 + l15] = f2bf(acc[i][2][reg]*qk_scale);
        orow[48 + l15] = f2bf(acc[i][3][reg]*qk_scale);
      }
    }
  }
}

// ---------------- Wo GEMM: fp32 out, flat grid 512, XCD-swizzled -----------
__global__ __launch_bounds__(256)
void gemm_wo(const u16* __restrict__ A, const u16* __restrict__ Bt, float* __restrict__ out){
  __shared__ __align__(16) u16 As[128*64];
  __shared__ __align__(16) u16 Bs[128*64];
  const int gblk = blockIdx.x;
  const int wid = (gblk & 7) * 64 + (gblk >> 3);
  const int bx = wid & 7, by = wid >> 3;
  const int tid = threadIdx.x;
  const int lane = tid & 63, w = tid >> 6;
  const int wr = w >> 1, wc = w & 1;
  const int l15 = lane & 15, lhi = lane >> 4;
  const int brow = by * 128;
  const int bcol = bx * 128;
  const int K = NSTATE;
  f32x4 acc[4][4] = {};

  for (int kt = 0; kt < K; kt += 64){
    #pragma unroll
    for (int it = 0; it < 4; ++it){
      int flat = it*4096 + tid*16;
      int row = flat >> 7, colb = flat & 127;
      gld_lds16(A + (size_t)(brow+row)*K + kt + (colb>>1), As + (flat>>1));
    }
    #pragma unroll
    for (int it = 0; it < 4; ++it){
      int flat = it*4096 + tid*16;
      int row = flat >> 7, colb = flat & 127;
      gld_lds16(Bt + (size_t)(bcol+row)*K + kt + (colb>>1), Bs + (flat>>1));
    }
    __syncthreads();
    #pragma unroll
    for (int ks = 0; ks < 2; ++ks){
      short8 av[4], bv[4];
      #pragma unroll
      for (int i = 0; i < 4; ++i)
        av[i] = *(const short8*)&As[(wr*64 + i*16 + l15)*64 + ks*32 + lhi*8];
      #pragma unroll
      for (int j = 0; j < 4; ++j)
        bv[j] = *(const short8*)&Bs[(wc*64 + j*16 + l15)*64 + ks*32 + lhi*8];
      #pragma unroll
      for (int i = 0; i < 4; ++i)
        #pragma unroll
        for (int j = 0; j < 4; ++j)
          acc[i][j] = mfma16x16(av[i], bv[j], acc[i][j]);
    }
    __syncthreads();
  }
  #pragma unroll
  for (int i = 0; i < 4; ++i)
    #pragma unroll
    for (int reg = 0; reg < 4; ++reg){
      int m = brow + wr*64 + i*16 + lhi*4 + reg;
      float* orow = out + (size_t)m*NSTATE + bcol + wc*64;
      #pragma unroll
      for (int j = 0; j < 4; ++j)
        orow[j*16 + l15] = acc[i][j][reg];
    }
}

// ---------------- causal flash attention -----------------------------------
// 256-thread blocks (4 waves). Wave w owns q-tile qt0+w (32 rows); the block
// processes complementary group pair (c, 15-c) sequentially -> exactly 34
// kv-iters per block (perfect balance). Grid 512, XCD-swizzled (8 bh/XCD).
// K and V staged cooperatively into LDS (double-buffered, global_load_lds,
// XOR-swizzled via inverse-swizzled global source per rule both-sides-or-
// neither). Schedule per iter: STAGE(buf^1) issue -> compute(buf) ->
// __syncthreads (drains vmcnt) -> flip. Speculative exp2 softmax (mrun=8)
// with exact fixup; P via per-wave XOR-swizzled LDS; setprio around MFMA.
__global__ __launch_bounds__(256)
void flash_attn(const u16* __restrict__ Q, const u16* __restrict__ Kh,
                const u16* __restrict__ Vt, u16* __restrict__ O){
  __shared__ __align__(16) u16 Kbuf[2][64*64];
  __shared__ __align__(16) u16 Vbuf[2][64*64];
  __shared__ __align__(16) u16 Pl4[4][32*64];
  const int gblk = blockIdx.x;
  const int xcd = gblk & 7, gr = gblk >> 3;      // 64 blocks per XCD
  const int bh = xcd*8 + (gr & 7);               // 8 consecutive bh per XCD
  const int c  = gr >> 3;                        // pair index 0..7
  const int tid = threadIdx.x;
  const int w = tid >> 6, lane = tid & 63;
  const int l15 = lane & 15, lhi = lane >> 4;
  const u16* Qb = Q  + (size_t)bh*NS*ND;
  const u16* Kb = Kh + (size_t)bh*NS*ND;
  const u16* Vb = Vt + (size_t)bh*ND*NS;
  const int b = bh >> 4, h = bh & 15;
  u16* Pl = &Pl4[w][0];

  int cur = 0;
  #pragma unroll 1
  for (int ph = 0; ph < 2; ++ph){
    const int qt0 = ph ? (60 - 4*c) : 4*c;
    const int qw  = (qt0 + w)*32;
    const int kend_w   = qw + 32;
    const int kend_blk = qt0*32 + 128;

    short8 qf[2][2];
    #pragma unroll
    for (int rf = 0; rf < 2; ++rf)
      #pragma unroll
      for (int ks = 0; ks < 2; ++ks)
        qf[rf][ks] = *(const short8*)&Qb[(size_t)(qw + rf*16 + l15)*ND + ks*32 + lhi*8];

    f32x4 oacc[2][4] = {};
    float mrun[2] = {8.0f, 8.0f};
    float lrun[2] = {0.f, 0.f};

    // prologue: stage kv=0 into buf[cur]
    #pragma unroll
    for (int i = 0; i < 2; ++i){
      int ch = i*256 + tid;
      int row = ch >> 3, cc = ch & 7;
      int scc = cc ^ (row & 7);
      gld_lds16(Kb + (size_t)row*ND + scc*8, &Kbuf[cur][ch*8]);
      gld_lds16(Vb + (size_t)row*NS + 0 + scc*8, &Vbuf[cur][ch*8]);
    }
    __syncthreads();

    #pragma unroll 1
    for (int kv0 = 0; kv0 < kend_blk; kv0 += 64){
      // ---- stage next kv-block into buf[cur^1] (lands under compute) ----
      if (kv0 + 64 < kend_blk){
        #pragma unroll
        for (int i = 0; i < 2; ++i){
          int ch = i*256 + tid;
          int row = ch >> 3, cc = ch & 7;
          int scc = cc ^ (row & 7);
          gld_lds16(Kb + (size_t)(kv0 + 64 + row)*ND + scc*8, &Kbuf[cur^1][ch*8]);
          gld_lds16(Vb + (size_t)row*NS + kv0 + 64 + scc*8, &Vbuf[cur^1][ch*8]);
        }
      }
      // ---- compute from buf[cur] (wave-uniform guard) ----
      if (kv0 < kend_w){
        const char* kb = (const char*)&Kbuf[cur][0];
        const char* vb = (const char*)&Vbuf[cur][0];
        short8 kf[8], vf[8];
        #pragma unroll
        for (int ks = 0; ks < 2; ++ks)
          #pragma unroll
          for (int cf = 0; cf < 4; ++cf){
            int row = cf*16 + l15;
            int off = (row*128 + ks*64 + lhi*16) ^ ((row & 7) << 4);
            kf[ks*4+cf] = *(const short8*)(kb + off);
            vf[ks*4+cf] = *(const short8*)(vb + off);
          }
        // S^T = K . Q^T : rows=k (lhi*4+reg), cols=q (l15)
        f32x4 st[2][4] = {};
        __builtin_amdgcn_s_setprio(1);
        #pragma unroll
        for (int ks = 0; ks < 2; ++ks)
          #pragma unroll
          for (int rf = 0; rf < 2; ++rf)
            #pragma unroll
            for (int cf = 0; cf < 4; ++cf)
              st[rf][cf] = mfma16x16(kf[ks*4+cf], qf[rf][ks], st[rf][cf]);
        __builtin_amdgcn_s_setprio(0);
        // causal mask
        if (kv0 + 63 > qw){
          #pragma unroll
          for (int rf = 0; rf < 2; ++rf){
            int qq = qw + rf*16 + l15;
            #pragma unroll
            for (int cf = 0; cf < 4; ++cf){
              int kb2 = kv0 + cf*16 + lhi*4;
              #pragma unroll
              for (int reg = 0; reg < 4; ++reg)
                if (kb2 + reg > qq) st[rf][cf][reg] = -3.0e30f;
            }
          }
        }
        // in-lane row-max tree (off critical path)
        float pmax[2], rs[2];
        #pragma unroll
        for (int rf = 0; rf < 2; ++rf){
          float c4[4];
          #pragma unroll
          for (int cf = 0; cf < 4; ++cf)
            c4[cf] = fmaxf(fmaxf(st[rf][cf][0], st[rf][cf][1]),
                           fmaxf(st[rf][cf][2], st[rf][cf][3]));
          pmax[rf] = fmaxf(fmaxf(c4[0], c4[1]), fmaxf(c4[2], c4[3]));
        }
        // speculative P = exp2(S - mrun)
        #pragma unroll
        for (int rf = 0; rf < 2; ++rf){
          #pragma unroll
          for (int cf = 0; cf < 4; ++cf)
            #pragma unroll
            for (int reg = 0; reg < 4; ++reg)
              st[rf][cf][reg] = EXP2(st[rf][cf][reg] - mrun[rf]);
          float s4[4];
          #pragma unroll
          for (int cf = 0; cf < 4; ++cf)
            s4[cf] = (st[rf][cf][0] + st[rf][cf][1]) + (st[rf][cf][2] + st[rf][cf][3]);
          rs[rf] = (s4[0] + s4[1]) + (s4[2] + s4[3]);
        }
        #pragma unroll
        for (int rf = 0; rf < 2; ++rf){
          pmax[rf] = fmaxf(pmax[rf], __shfl_xor(pmax[rf], 16));
          pmax[rf] = fmaxf(pmax[rf], __shfl_xor(pmax[rf], 32));
          rs[rf] += __shfl_xor(rs[rf], 16);
          rs[rf] += __shfl_xor(rs[rf], 32);
        }
        // rare exact fixup
        bool need = (pmax[0] > mrun[0]) || (pmax[1] > mrun[1]);
        if (__any(need)){
          #pragma unroll
          for (int rf = 0; rf < 2; ++rf){
            float mn = fmaxf(mrun[rf], pmax[rf]);
            float a  = EXP2(mrun[rf] - mn);
            mrun[rf] = mn;
            lrun[rf] = (lrun[rf] + rs[rf]) * a;
            #pragma unroll
            for (int cf = 0; cf < 4; ++cf)
              #pragma unroll
              for (int reg = 0; reg < 4; ++reg)
                st[rf][cf][reg] *= a;
            #pragma unroll
            for (int reg = 0; reg < 4; ++reg){
              float aT = __shfl(a, lhi*4 + reg, 64);
              #pragma unroll
              for (int df = 0; df < 4; ++df)
                oacc[rf][df][reg] *= aT;
            }
          }
        } else {
          lrun[0] += rs[0];
          lrun[1] += rs[1];
        }
        // pack P -> LDS (XOR-swizzled rows)
        #pragma unroll
        for (int rf = 0; rf < 2; ++rf){
          int row = rf*16 + l15;
          #pragma unroll
          for (int cf = 0; cf < 4; ++cf){
            uint2 pk;
            pk.x = cvtpk(st[rf][cf][0], st[rf][cf][1]);
            pk.y = cvtpk(st[rf][cf][2], st[rf][cf][3]);
            int bo = ((row<<7) + ((cf*16 + lhi*4)<<1)) ^ ((row&7)<<4);
            *(uint2*)((char*)Pl + bo) = pk;
          }
        }
        // O += P . V
        #pragma unroll
        for (int ks = 0; ks < 2; ++ks){
          short8 pf[2];
          #pragma unroll
          for (int rf = 0; rf < 2; ++rf){
            int row = rf*16 + l15;
            int bo = ((row<<7) + ((ks*32 + lhi*8)<<1)) ^ ((row&7)<<4);
            pf[rf] = *(const short8*)((const char*)Pl + bo);
          }
          __builtin_amdgcn_s_setprio(1);
          #pragma unroll
          for (int rf = 0; rf < 2; ++rf)
            #pragma unroll
            for (int df = 0; df < 4; ++df)
              oacc[rf][df] = mfma16x16(pf[rf], vf[ks*4+df], oacc[rf][df]);
          __builtin_amdgcn_s_setprio(0);
        }
      }
      __syncthreads();   // drains vmcnt(0)+lgkmcnt(0): staged buf ready, all reads done
      cur ^= 1;
    }

    // epilogue: O/l -> [B,S,H*D] bf16
    #pragma unroll
    for (int rf = 0; rf < 2; ++rf){
      float inv = 1.0f / lrun[rf];
      #pragma unroll
      for (int reg = 0; reg < 4; ++reg){
        float invT = __shfl(inv, lhi*4 + reg, 64);
        int qrow = qw + rf*16 + lhi*4 + reg;
        u16* orow = O + ((size_t)(b*NS + qrow))*NSTATE + h*ND;
        #pragma unroll
        for (int df = 0; df < 4; ++df)
          orow[df*16 + l15] = f2bf(oacc[rf][df][reg] * invT);
      }
    }
  }
}

// ---------------------------------------------------------------------------
extern "C" void kernel_launch(void* const* d_in, const int* in_sizes, int n_in,
                              void* d_out, int out_size, void* d_ws, size_t ws_size,
                              hipStream_t stream){
  const float* q_src = (const float*)d_in[0];
  const float* k_src = (const float*)d_in[1];
  const float* v_src = (const float*)d_in[2];
  // d_in[3] = position_mask (causal, statically known) — unused
  const float* Wq = (const float*)d_in[4];
  const float* Wk = (const float*)d_in[5];
  const float* Wv = (const float*)d_in[6];
  const float* Wo = (const float*)d_in[7];

  char* ws = (char*)d_ws;
  const size_t MB = 1u << 20;
  if (ws_size < 104*MB) return;   // need 104 MB of scratch

  u16* xq   = (u16*)(ws +  0*MB);   // 16 MB  (bf16 q_src)
  u16* xk   = (u16*)(ws + 16*MB);   // 16 MB  (bf16 k_src)   -> reused as attn out
  u16* xv   = (u16*)(ws + 32*MB);   // 16 MB  (bf16 v_src)
  u16* wq16 = (u16*)(ws + 48*MB);   //  2 MB  } contiguous => Wcat [3072][1024]
  u16* wk16 = (u16*)(ws + 50*MB);   //  2 MB  }
  u16* wv16 = (u16*)(ws + 52*MB);   //  2 MB  }
  u16* wo16 = (u16*)(ws + 54*MB);   //  2 MB
  u16* Qh   = (u16*)(ws + 56*MB);   // 16 MB  [B,H,S,D]
  u16* Kk   = (u16*)(ws + 72*MB);   // 16 MB  [B,H,S,D]
  u16* Vt   = (u16*)(ws + 88*MB);   // 16 MB  [B,H,D,S]  (direct from gemm_qkv)
  u16* Oat  = xk;                   // [B,S,H*D]  (xk dead after QKV gemm)

  cvt_all<<<dim3(28672), dim3(256), 0, stream>>>(q_src, k_src, v_src, Wq, Wk, Wv, Wo,
                                                 xq, xk, xv, wq16, wk16, wv16, wo16);
  gemm_qkv<<<dim3(1536), dim3(256), 0, stream>>>(xq, xk, xv, wq16, Qh, Kk, Vt);
  flash_attn<<<dim3(512), dim3(256), 0, stream>>>(Qh, Kk, Vt, Oat);
  gemm_wo<<<dim3(512), dim3(256), 0, stream>>>(Oat, wo16, (float*)d_out);
}

// Round 9
// 215.958 us; speedup vs baseline: 3.7116x; 1.2024x over previous
//
#include <hip/hip_runtime.h>

typedef unsigned short u16;
typedef unsigned int u32;
typedef short short8 __attribute__((ext_vector_type(8)));
typedef float f32x4 __attribute__((ext_vector_type(4)));
typedef float f32x16 __attribute__((ext_vector_type(16)));

#define NB 4
#define NS 2048
#define NSTATE 1024
#define NH 16
#define ND 64
#define NM (NB*NS)   // 8192 rows

#if __has_builtin(__builtin_amdgcn_exp2f)
#define EXP2(x) __builtin_amdgcn_exp2f(x)
#else
#define EXP2(x) __expf((x) * 0.6931471805599453f)
#endif

__device__ __forceinline__ u16 f2bf(float f){
  union { float fv; unsigned uv; } x; x.fv = f;
  unsigned r = x.uv + 0x7fffu + ((x.uv >> 16) & 1u);
  return (u16)(r >> 16);
}

__device__ __forceinline__ u32 cvtpk(float lo, float hi){
  u32 r;
  asm("v_cvt_pk_bf16_f32 %0, %1, %2" : "=v"(r) : "v"(lo), "v"(hi));
  return r;
}

__device__ __forceinline__ f32x4 mfma16x16(short8 a, short8 b, f32x4 c){
  return __builtin_amdgcn_mfma_f32_16x16x32_bf16(a, b, c, 0, 0, 0);
}

__device__ __forceinline__ f32x16 mfma32(short8 a, short8 b, f32x16 c){
  return __builtin_amdgcn_mfma_f32_32x32x16_bf16(a, b, c, 0, 0, 0);
}

__device__ __forceinline__ void gld_lds16(const u16* g, u16* l){
  __builtin_amdgcn_global_load_lds((const __attribute__((address_space(1))) void*)g,
                                   (__attribute__((address_space(3))) void*)l, 16, 0, 0);
}

// ---------------- fp32 -> bf16 conversion for 3 activations + 4 weights ----
__global__ __launch_bounds__(256)
void cvt_all(const float* __restrict__ q, const float* __restrict__ k, const float* __restrict__ v,
             const float* __restrict__ wq, const float* __restrict__ wk,
             const float* __restrict__ wv, const float* __restrict__ wo,
             u16* oq, u16* ok, u16* ov, u16* owq, u16* owk, u16* owv, u16* owo){
  const int XN4 = (NB*NS*NSTATE)/4;   // 2097152
  const int WN4 = (NSTATE*NSTATE)/4;  // 262144
  int gid = blockIdx.x * 256 + threadIdx.x;
  const float* src; u16* dst; int idx;
  if (gid < XN4)          { src = q; dst = oq; idx = gid; }
  else if (gid < 2*XN4)   { src = k; dst = ok; idx = gid - XN4; }
  else if (gid < 3*XN4)   { src = v; dst = ov; idx = gid - 2*XN4; }
  else {
    int g = gid - 3*XN4;
    int wsel = g >> 18;       // / WN4
    idx = g & (WN4 - 1);
    src = (wsel==0)?wq:(wsel==1)?wk:(wsel==2)?wv:wo;
    dst = (wsel==0)?owq:(wsel==1)?owk:(wsel==2)?owv:owo;
  }
  float4 val = ((const float4*)src)[idx];
  ushort4 r;
  r.x = f2bf(val.x); r.y = f2bf(val.y); r.z = f2bf(val.z); r.w = f2bf(val.w);
  ((ushort4*)dst)[idx] = r;
}

// ---------------- merged QKV projection GEMM -------------------------------
// Output cols [0,1024)=Q(RoPE), [1024,2048)=K(RoPE), [2048,3072)=V (written
// DIRECTLY transposed to Vt[B,H,D,S] from the fragment layout).
// Flat grid 1536, XCD-swizzled (8 row-panels per XCD).
__global__ __launch_bounds__(256)
void gemm_qkv(const u16* __restrict__ xq, const u16* __restrict__ xk,
              const u16* __restrict__ xv, const u16* __restrict__ Wcat,
              u16* __restrict__ Qh, u16* __restrict__ Kk, u16* __restrict__ Vt){
  __shared__ __align__(16) u16 As[128*64];
  __shared__ __align__(16) u16 Bs[128*64];
  const int gblk = blockIdx.x;
  const int wid = (gblk & 7) * 192 + (gblk >> 3);
  const int bx = wid % 24, by = wid / 24;
  const int sel = bx >> 3;                        // 0=Q 1=K 2=V
  const u16* A = (sel==0) ? xq : (sel==1) ? xk : xv;
  const int tid = threadIdx.x;
  const int lane = tid & 63, w = tid >> 6;
  const int wr = w >> 1, wc = w & 1;
  const int l15 = lane & 15, lhi = lane >> 4;
  const int brow = by * 128;
  const int bcol = bx * 128;                      // global col in [0,3072)
  const int K = NSTATE;
  f32x4 acc[4][4] = {};

  for (int kt = 0; kt < K; kt += 64){
    #pragma unroll
    for (int it = 0; it < 4; ++it){
      int flat = it*4096 + tid*16;
      int row = flat >> 7, colb = flat & 127;
      gld_lds16(A + (size_t)(brow+row)*K + kt + (colb>>1), As + (flat>>1));
    }
    #pragma unroll
    for (int it = 0; it < 4; ++it){
      int flat = it*4096 + tid*16;
      int row = flat >> 7, colb = flat & 127;
      gld_lds16(Wcat + (size_t)(bcol+row)*K + kt + (colb>>1), Bs + (flat>>1));
    }
    __syncthreads();
    #pragma unroll
    for (int ks = 0; ks < 2; ++ks){
      short8 av[4], bv[4];
      #pragma unroll
      for (int i = 0; i < 4; ++i)
        av[i] = *(const short8*)&As[(wr*64 + i*16 + l15)*64 + ks*32 + lhi*8];
      #pragma unroll
      for (int j = 0; j < 4; ++j)
        bv[j] = *(const short8*)&Bs[(wc*64 + j*16 + l15)*64 + ks*32 + lhi*8];
      #pragma unroll
      for (int i = 0; i < 4; ++i)
        #pragma unroll
        for (int j = 0; j < 4; ++j)
          acc[i][j] = mfma16x16(av[i], bv[j], acc[i][j]);
    }
    __syncthreads();
  }

  const int col0 = bcol + wc*64;                  // wave's 64-col slab (one head)
  if (sel == 2){
    // V -> Vt[B,H,D,S] directly: d = j*16+l15, s0 = (m of reg 0) & 2047.
    const int head = (col0 & 1023) >> 6;
    #pragma unroll
    for (int i = 0; i < 4; ++i){
      int m0 = brow + wr*64 + i*16 + lhi*4;       // reg 0 row (4 consecutive s)
      int b = m0 >> 11, s0 = m0 & (NS-1);
      u16* obase = Vt + ((size_t)((b*NH + head)*ND))*NS + s0;
      #pragma unroll
      for (int j = 0; j < 4; ++j){
        int d = j*16 + l15;
        uint2 pk;
        pk.x = cvtpk(acc[i][j][0], acc[i][j][1]);
        pk.y = cvtpk(acc[i][j][2], acc[i][j][3]);
        *(uint2*)(obase + (size_t)d*NS) = pk;
      }
    }
  } else {
    // Q/K: scale (incl sqrt(log2e)) + RoPE, write [B,H,S,D]
    u16* out = sel ? Kk : Qh;
    const float qk_scale = 0.4246609f;            // (1/8)^0.5 * sqrt(log2 e)
    const int head = (col0 & 1023) >> 6;
    const float invf = __powf(10000.0f, -(float)l15 * (1.0f/16.0f));
    #pragma unroll
    for (int i = 0; i < 4; ++i){
      #pragma unroll
      for (int reg = 0; reg < 4; ++reg){
        int m = brow + wr*64 + i*16 + lhi*4 + reg;
        int b = m >> 11, s = m & (NS-1);
        float sn, cs;
        __sincosf((float)s * invf, &sn, &cs);
        float x0 = acc[i][0][reg]*qk_scale;
        float x1 = acc[i][1][reg]*qk_scale;
        u16* orow = out + ((size_t)(b*NH + head)*NS + s)*ND;
        orow[ 0 + l15] = f2bf(x0*cs - x1*sn);
        orow[16 + l15] = f2bf(x1*cs + x0*sn);
        orow[32 + l15] = f2bf(acc[i][2][reg]*qk_scale);
        orow[48 + l15] = f2bf(acc[i][3][reg]*qk_scale);
      }
    }
  }
}

// ---------------- Wo GEMM: fp32 out, flat grid 512, XCD-swizzled -----------
__global__ __launch_bounds__(256)
void gemm_wo(const u16* __restrict__ A, const u16* __restrict__ Bt, float* __restrict__ out){
  __shared__ __align__(16) u16 As[128*64];
  __shared__ __align__(16) u16 Bs[128*64];
  const int gblk = blockIdx.x;
  const int wid = (gblk & 7) * 64 + (gblk >> 3);
  const int bx = wid & 7, by = wid >> 3;
  const int tid = threadIdx.x;
  const int lane = tid & 63, w = tid >> 6;
  const int wr = w >> 1, wc = w & 1;
  const int l15 = lane & 15, lhi = lane >> 4;
  const int brow = by * 128;
  const int bcol = bx * 128;
  const int K = NSTATE;
  f32x4 acc[4][4] = {};

  for (int kt = 0; kt < K; kt += 64){
    #pragma unroll
    for (int it = 0; it < 4; ++it){
      int flat = it*4096 + tid*16;
      int row = flat >> 7, colb = flat & 127;
      gld_lds16(A + (size_t)(brow+row)*K + kt + (colb>>1), As + (flat>>1));
    }
    #pragma unroll
    for (int it = 0; it < 4; ++it){
      int flat = it*4096 + tid*16;
      int row = flat >> 7, colb = flat & 127;
      gld_lds16(Bt + (size_t)(bcol+row)*K + kt + (colb>>1), Bs + (flat>>1));
    }
    __syncthreads();
    #pragma unroll
    for (int ks = 0; ks < 2; ++ks){
      short8 av[4], bv[4];
      #pragma unroll
      for (int i = 0; i < 4; ++i)
        av[i] = *(const short8*)&As[(wr*64 + i*16 + l15)*64 + ks*32 + lhi*8];
      #pragma unroll
      for (int j = 0; j < 4; ++j)
        bv[j] = *(const short8*)&Bs[(wc*64 + j*16 + l15)*64 + ks*32 + lhi*8];
      #pragma unroll
      for (int i = 0; i < 4; ++i)
        #pragma unroll
        for (int j = 0; j < 4; ++j)
          acc[i][j] = mfma16x16(av[i], bv[j], acc[i][j]);
    }
    __syncthreads();
  }
  #pragma unroll
  for (int i = 0; i < 4; ++i)
    #pragma unroll
    for (int reg = 0; reg < 4; ++reg){
      int m = brow + wr*64 + i*16 + lhi*4 + reg;
      float* orow = out + (size_t)m*NSTATE + bcol + wc*64;
      #pragma unroll
      for (int j = 0; j < 4; ++j)
        orow[j*16 + l15] = acc[i][j][reg];
    }
}

// ---------------- causal flash attention (32x32 swapped-QK, T12) ----------
// 256-thread blocks (4 waves), grid 1024: block = group g of 4 q-tiles (32
// rows each, wave w owns q-tile g*4+w). Long groups launch first; XCD swizzle
// (8 bh per XCD). K/V double-buffered in LDS (global_load_lds, XOR swizzle
// via inverse-swizzled global source). st = mfma32(K, Q): lane owns q=lane&31
// (partner lane&31 same q, other 16 k's) -> softmax fully lane-local except
// two shfl_xor(32). P packed in-register: cvt_pk pairs + v_permlane32_swap
// produce PV B-fragments directly (no P LDS). PV = mfma32(V, P) -> oacc col
// = q = lane&31, so rescale + epilogue divide lane-local. Speculative exp2
// (mrun=8) with exact rare fixup. No VGPR cap (R5/R6 lesson).
__global__ __launch_bounds__(256)
void flash_attn(const u16* __restrict__ Q, const u16* __restrict__ Kh,
                const u16* __restrict__ Vt, u16* __restrict__ O){
  __shared__ __align__(16) u16 Kbuf[2][64*64];
  __shared__ __align__(16) u16 Vbuf[2][64*64];
  const int gblk = blockIdx.x;
  const int xcd = gblk & 7, gr = gblk >> 3;     // 128 blocks per XCD
  const int bh  = xcd*8 + (gr & 7);             // 8 consecutive bh per XCD
  const int g   = 15 - (gr >> 3);               // long groups first
  const int tid = threadIdx.x;
  const int w = tid >> 6, lane = tid & 63;
  const int l31 = lane & 31, hi = lane >> 5;
  const u16* Qb = Q  + (size_t)bh*NS*ND;
  const u16* Kb = Kh + (size_t)bh*NS*ND;
  const u16* Vb = Vt + (size_t)bh*ND*NS;
  const int b = bh >> 4, h = bh & 15;
  const int qw = g*128 + w*32;
  const int kend_w   = qw + 32;
  const int kend_blk = g*128 + 128;

  // Q B-operand fragments: lane row = q = qw + l31, elems d = dd*16 + hi*8 ..
  short8 qf[4];
  #pragma unroll
  for (int dd = 0; dd < 4; ++dd)
    qf[dd] = *(const short8*)&Qb[(size_t)(qw + l31)*ND + dd*16 + hi*8];

  f32x16 oacc[2] = {};          // O^T halves: lane holds O[d=crow(r,hi)+32*dh][q=l31]
  float mrun = 8.0f, lrun = 0.f;

  int cur = 0;
  // prologue: stage kv=0
  #pragma unroll
  for (int i = 0; i < 2; ++i){
    int ch = i*256 + tid;
    int row = ch >> 3, cc = ch & 7;
    int scc = cc ^ (row & 7);
    gld_lds16(Kb + (size_t)row*ND + scc*8, &Kbuf[cur][ch*8]);
    gld_lds16(Vb + (size_t)row*NS + scc*8, &Vbuf[cur][ch*8]);
  }
  __syncthreads();

  #pragma unroll 1
  for (int kv0 = 0; kv0 < kend_blk; kv0 += 64){
    // ---- stage next kv-block into buf[cur^1] (lands under compute) ----
    if (kv0 + 64 < kend_blk){
      #pragma unroll
      for (int i = 0; i < 2; ++i){
        int ch = i*256 + tid;
        int row = ch >> 3, cc = ch & 7;
        int scc = cc ^ (row & 7);
        gld_lds16(Kb + (size_t)(kv0 + 64 + row)*ND + scc*8, &Kbuf[cur^1][ch*8]);
        gld_lds16(Vb + (size_t)row*NS + kv0 + 64 + scc*8, &Vbuf[cur^1][ch*8]);
      }
    }
    // ---- compute from buf[cur] (wave-uniform guard) ----
    if (kv0 < kend_w){
      const char* kb = (const char*)&Kbuf[cur][0];
      const char* vb = (const char*)&Vbuf[cur][0];
      // QK^T: st0 covers k in [kv0,kv0+32), st1 [kv0+32,kv0+64)
      short8 kf[8];
      #pragma unroll
      for (int kh2 = 0; kh2 < 2; ++kh2)
        #pragma unroll
        for (int dd = 0; dd < 4; ++dd){
          int srow = kh2*32 + l31;
          int off = (srow*128 + dd*32 + hi*16) ^ ((srow & 7) << 4);
          kf[kh2*4+dd] = *(const short8*)(kb + off);
        }
      f32x16 st0 = {}, st1 = {};
      __builtin_amdgcn_s_setprio(1);
      #pragma unroll
      for (int dd = 0; dd < 4; ++dd) st0 = mfma32(kf[dd],   qf[dd], st0);
      #pragma unroll
      for (int dd = 0; dd < 4; ++dd) st1 = mfma32(kf[4+dd], qf[dd], st1);
      __builtin_amdgcn_s_setprio(0);
      // causal mask (diagonal blocks only): k = kv0 + 32*half + crow(r,hi)
      if (kv0 + 63 > qw){
        int q = qw + l31;
        #pragma unroll
        for (int r2 = 0; r2 < 16; ++r2){
          int k0 = kv0 + (r2 & 3) + 8*(r2 >> 2) + 4*hi;
          if (k0      > q) st0[r2] = -3.0e30f;
          if (k0 + 32 > q) st1[r2] = -3.0e30f;
        }
      }
      // row max (lane-local; combine partner via shfl_xor 32)
      float m0 = fmaxf(fmaxf(st0[0], st0[1]), fmaxf(st0[2], st0[3]));
      float m1 = fmaxf(fmaxf(st0[4], st0[5]), fmaxf(st0[6], st0[7]));
      float m2 = fmaxf(fmaxf(st0[8], st0[9]), fmaxf(st0[10], st0[11]));
      float m3 = fmaxf(fmaxf(st0[12], st0[13]), fmaxf(st0[14], st0[15]));
      float m4 = fmaxf(fmaxf(st1[0], st1[1]), fmaxf(st1[2], st1[3]));
      float m5 = fmaxf(fmaxf(st1[4], st1[5]), fmaxf(st1[6], st1[7]));
      float m6 = fmaxf(fmaxf(st1[8], st1[9]), fmaxf(st1[10], st1[11]));
      float m7 = fmaxf(fmaxf(st1[12], st1[13]), fmaxf(st1[14], st1[15]));
      float pm = fmaxf(fmaxf(fmaxf(m0, m1), fmaxf(m2, m3)),
                       fmaxf(fmaxf(m4, m5), fmaxf(m6, m7)));
      pm = fmaxf(pm, __shfl_xor(pm, 32));
      // speculative P = exp2(S - mrun); row sum
      #pragma unroll
      for (int r2 = 0; r2 < 16; ++r2){
        st0[r2] = EXP2(st0[r2] - mrun);
        st1[r2] = EXP2(st1[r2] - mrun);
      }
      float s0 = 0.f, s1 = 0.f, s2 = 0.f, s3 = 0.f;
      #pragma unroll
      for (int r2 = 0; r2 < 16; r2 += 4){
        s0 += st0[r2+0] + st1[r2+0];
        s1 += st0[r2+1] + st1[r2+1];
        s2 += st0[r2+2] + st1[r2+2];
        s3 += st0[r2+3] + st1[r2+3];
      }
      float rs = (s0 + s1) + (s2 + s3);
      rs += __shfl_xor(rs, 32);
      // rare exact fixup (all lane-local)
      if (__any(pm > mrun)){
        float mn = fmaxf(mrun, pm);
        float a  = EXP2(mrun - mn);
        mrun = mn;
        lrun = (lrun + rs) * a;
        #pragma unroll
        for (int r2 = 0; r2 < 16; ++r2){
          st0[r2] *= a; st1[r2] *= a;
          oacc[0][r2] *= a; oacc[1][r2] *= a;
        }
      } else {
        lrun += rs;
      }
      // pack P -> PV B-fragments in-register (cvt_pk + permlane32_swap)
      short8 paf[4];
      #pragma unroll
      for (int sl = 0; sl < 4; ++sl){
        const f32x16& S = (sl < 2) ? st0 : st1;
        const int base = (sl & 1) * 8;
        u32 a0 = cvtpk(S[base+0], S[base+1]);
        u32 b0 = cvtpk(S[base+4], S[base+5]);
        asm("v_permlane32_swap_b32 %0, %1" : "+v"(a0), "+v"(b0));
        u32 a1 = cvtpk(S[base+2], S[base+3]);
        u32 b1 = cvtpk(S[base+6], S[base+7]);
        asm("v_permlane32_swap_b32 %0, %1" : "+v"(a1), "+v"(b1));
        union { u32 u[4]; short8 v; } pk_;
        pk_.u[0] = a0; pk_.u[1] = a1; pk_.u[2] = b0; pk_.u[3] = b1;
        paf[sl] = pk_.v;
      }
      // O^T += V^T . P : A=V (rows=d), B=P (rows=q) -> oacc col = q
      #pragma unroll
      for (int dh = 0; dh < 2; ++dh){
        short8 vv[4];
        #pragma unroll
        for (int sl = 0; sl < 4; ++sl){
          int drow = dh*32 + l31;
          int off = (drow*128 + sl*32 + hi*16) ^ ((drow & 7) << 4);
          vv[sl] = *(const short8*)(vb + off);
        }
        __builtin_amdgcn_s_setprio(1);
        #pragma unroll
        for (int sl = 0; sl < 4; ++sl)
          oacc[dh] = mfma32(vv[sl], paf[sl], oacc[dh]);
        __builtin_amdgcn_s_setprio(0);
      }
    }
    __syncthreads();   // staged buf ready; all reads of cur done
    cur ^= 1;
  }

  // epilogue: O[q][d] = oacc/lrun ; lane q = qw+l31, d = crow(r,hi)+32*dh
  float inv = 1.0f / lrun;
  u16* orow = O + ((size_t)(b*NS + qw + l31))*NSTATE + h*ND;
  #pragma unroll
  for (int dh = 0; dh < 2; ++dh)
    #pragma unroll
    for (int rq = 0; rq < 4; ++rq){
      uint2 pk;
      pk.x = cvtpk(oacc[dh][rq*4+0]*inv, oacc[dh][rq*4+1]*inv);
      pk.y = cvtpk(oacc[dh][rq*4+2]*inv, oacc[dh][rq*4+3]*inv);
      *(uint2*)(orow + dh*32 + rq*8 + hi*4) = pk;
    }
}

// ---------------------------------------------------------------------------
extern "C" void kernel_launch(void* const* d_in, const int* in_sizes, int n_in,
                              void* d_out, int out_size, void* d_ws, size_t ws_size,
                              hipStream_t stream){
  const float* q_src = (const float*)d_in[0];
  const float* k_src = (const float*)d_in[1];
  const float* v_src = (const float*)d_in[2];
  // d_in[3] = position_mask (causal, statically known) — unused
  const float* Wq = (const float*)d_in[4];
  const float* Wk = (const float*)d_in[5];
  const float* Wv = (const float*)d_in[6];
  const float* Wo = (const float*)d_in[7];

  char* ws = (char*)d_ws;
  const size_t MB = 1u << 20;
  if (ws_size < 104*MB) return;   // need 104 MB of scratch

  u16* xq   = (u16*)(ws +  0*MB);   // 16 MB  (bf16 q_src)
  u16* xk   = (u16*)(ws + 16*MB);   // 16 MB  (bf16 k_src)   -> reused as attn out
  u16* xv   = (u16*)(ws + 32*MB);   // 16 MB  (bf16 v_src)
  u16* wq16 = (u16*)(ws + 48*MB);   //  2 MB  } contiguous => Wcat [3072][1024]
  u16* wk16 = (u16*)(ws + 50*MB);   //  2 MB  }
  u16* wv16 = (u16*)(ws + 52*MB);   //  2 MB  }
  u16* wo16 = (u16*)(ws + 54*MB);   //  2 MB
  u16* Qh   = (u16*)(ws + 56*MB);   // 16 MB  [B,H,S,D]
  u16* Kk   = (u16*)(ws + 72*MB);   // 16 MB  [B,H,S,D]
  u16* Vt   = (u16*)(ws + 88*MB);   // 16 MB  [B,H,D,S]  (direct from gemm_qkv)
  u16* Oat  = xk;                   // [B,S,H*D]  (xk dead after QKV gemm)

  cvt_all<<<dim3(28672), dim3(256), 0, stream>>>(q_src, k_src, v_src, Wq, Wk, Wv, Wo,
                                                 xq, xk, xv, wq16, wk16, wv16, wo16);
  gemm_qkv<<<dim3(1536), dim3(256), 0, stream>>>(xq, xk, xv, wq16, Qh, Kk, Vt);
  flash_attn<<<dim3(1024), dim3(256), 0, stream>>>(Qh, Kk, Vt, Oat);
  gemm_wo<<<dim3(512), dim3(256), 0, stream>>>(Oat, wo16, (float*)d_out);
}